// Round 2
// baseline (6930.444 us; speedup 1.0000x reference)
//
#include <hip/hip_runtime.h>
#include <math.h>

#define B 8
#define C 128
#define HEADS 8
#define HD 16
#define HH 128
#define WW 128
#define P 16384          // HH*WW

static __device__ __forceinline__ float PI2F() { return 6.28318530717958647692f; }

// ---------------------------------------------------------------------------
// Forward DFT-128 along contiguous (w) axis; real input. One block per row.
__global__ void k_dft_rows_fwd(const float* __restrict__ x,
                               float* __restrict__ outR, float* __restrict__ outI) {
    int row = blockIdx.x;
    int k = threadIdx.x;             // 0..127
    long base = (long)row * 128;
    float a = -PI2F() * (float)k / 128.0f;
    float cs = cosf(a), sn = sinf(a);
    float twr = 1.f, twi = 0.f, ar = 0.f, ai = 0.f;
    for (int w = 0; w < 128; ++w) {
        float xv = x[base + w];      // lane-uniform -> scalar load
        ar = fmaf(xv, twr, ar);
        ai = fmaf(xv, twi, ai);
        float nr = fmaf(twr, cs, -twi * sn);
        twi = fmaf(twr, sn, twi * cs);
        twr = nr;
    }
    outR[base + k] = ar;
    outI[base + k] = ai;
}

// ---------------------------------------------------------------------------
// DFT-128 along strided (row-index) axis of a 128x128 complex image.
// out[k][lane] = sum_h in[h][lane] * e^{SIGN*2pi*i*h*k/128}
template<int SIGN>
__global__ void k_dft_cols(const float* __restrict__ inR, const float* __restrict__ inI,
                           float* __restrict__ outR, float* __restrict__ outI) {
    __shared__ float2 tw[128];
    int img = blockIdx.x >> 3;
    int kg  = blockIdx.x & 7;
    int lane = threadIdx.x;          // 0..127
    {
        float a = PI2F() * (float)lane / 128.0f;
        tw[lane] = make_float2(cosf(a), SIGN > 0 ? sinf(a) : -sinf(a));
    }
    __syncthreads();
    long base = (long)img * P;
    float accR[16], accI[16];
    #pragma unroll
    for (int j = 0; j < 16; ++j) { accR[j] = 0.f; accI[j] = 0.f; }
    for (int h = 0; h < 128; ++h) {
        float xr = inR[base + h*128 + lane];
        float xi = inI[base + h*128 + lane];
        #pragma unroll
        for (int j = 0; j < 16; ++j) {
            int k = kg*16 + j;
            float2 t = tw[(h*k) & 127];        // wave-uniform LDS broadcast
            accR[j] = fmaf(xr, t.x, fmaf(-xi, t.y, accR[j]));
            accI[j] = fmaf(xr, t.y, fmaf( xi, t.x, accI[j]));
        }
    }
    #pragma unroll
    for (int j = 0; j < 16; ++j) {
        int k = kg*16 + j;
        outR[base + k*128 + lane] = accR[j];
        outI[base + k*128 + lane] = accI[j];
    }
}

// ---------------------------------------------------------------------------
// SE gate stage 1: M[b,j,p] = relu(bn(b1[j] + sum_c W1[j][c]*XFr[b,c,p]))
__global__ void k_gate_mid(const float* __restrict__ XFr, const float* __restrict__ w1,
                           const float* __restrict__ b1, const float* __restrict__ gamma,
                           const float* __restrict__ beta, const float* __restrict__ mean,
                           const float* __restrict__ var, float* __restrict__ M) {
    __shared__ float w1s[8*128];
    int tid = threadIdx.x;
    for (int i = tid; i < 1024; i += 256) w1s[i] = w1[i];
    __syncthreads();
    long idx = (long)blockIdx.x * 256 + tid;   // over NB*P (blocks don't straddle b)
    int b = (int)(idx >> 14);
    int p = (int)(idx & 16383);
    float acc[8];
    #pragma unroll
    for (int j = 0; j < 8; ++j) acc[j] = b1[j];
    const float* xb = XFr + (long)b * C * P + p;
    for (int c = 0; c < 128; ++c) {
        float xv = xb[(long)c * P];
        #pragma unroll
        for (int j = 0; j < 8; ++j) acc[j] = fmaf(w1s[j*128 + c], xv, acc[j]);
    }
    #pragma unroll
    for (int j = 0; j < 8; ++j) {
        float v = (acc[j] - mean[j]) * rsqrtf(var[j] + 1e-5f) * gamma[j] + beta[j];
        M[((long)b*8 + j)*P + p] = fmaxf(v, 0.f);
    }
}

// ---------------------------------------------------------------------------
// Gate stage 2 fused with IDFT-128 along h: out = IDFT_h( sigmoid(W2*M+b2) * XF )
__global__ void k_gate_idft_h(const float* __restrict__ XFr, const float* __restrict__ XFi,
                              const float* __restrict__ Mg, const float* __restrict__ w2,
                              const float* __restrict__ b2,
                              float* __restrict__ outR, float* __restrict__ outI) {
    __shared__ float2 tw[128];
    int img = blockIdx.x >> 3;       // b*128 + c (chunk-local)
    int kg  = blockIdx.x & 7;
    int lane = threadIdx.x;
    {
        float a = PI2F() * (float)lane / 128.0f;
        tw[lane] = make_float2(cosf(a), sinf(a));   // sign +
    }
    __syncthreads();
    int b = img >> 7, c = img & 127;
    float w2r[8];
    #pragma unroll
    for (int j = 0; j < 8; ++j) w2r[j] = w2[c*8 + j];
    float b2c = b2[c];
    long base = (long)img * P;
    const float* mb = Mg + (long)b*8*P;
    float accR[16], accI[16];
    #pragma unroll
    for (int j = 0; j < 16; ++j) { accR[j] = 0.f; accI[j] = 0.f; }
    for (int h = 0; h < 128; ++h) {
        int off = h*128 + lane;
        float z = b2c;
        #pragma unroll
        for (int j = 0; j < 8; ++j) z = fmaf(w2r[j], mb[(long)j*P + off], z);
        float g = 1.0f / (1.0f + expf(-z));
        float xr = g * XFr[base + off];
        float xi = g * XFi[base + off];
        #pragma unroll
        for (int j = 0; j < 16; ++j) {
            int k = kg*16 + j;
            float2 t = tw[(h*k) & 127];
            accR[j] = fmaf(xr, t.x, fmaf(-xi, t.y, accR[j]));
            accI[j] = fmaf(xr, t.y, fmaf( xi, t.x, accI[j]));
        }
    }
    #pragma unroll
    for (int j = 0; j < 16; ++j) {
        int k = kg*16 + j;
        outR[base + k*128 + lane] = accR[j];
        outI[base + k*128 + lane] = accI[j];
    }
}

// ---------------------------------------------------------------------------
// IDFT-128 along contiguous axis + 1/16384 scale + abs
__global__ void k_idft_rows_abs(const float* __restrict__ inR, const float* __restrict__ inI,
                                float* __restrict__ out) {
    int row = blockIdx.x;
    int k = threadIdx.x;
    long base = (long)row * 128;
    float a = PI2F() * (float)k / 128.0f;
    float cs = cosf(a), sn = sinf(a);
    float twr = 1.f, twi = 0.f, ar = 0.f, ai = 0.f;
    for (int w = 0; w < 128; ++w) {
        float xr = inR[base + w], xi = inI[base + w];   // lane-uniform
        ar = fmaf(xr, twr, fmaf(-xi, twi, ar));
        ai = fmaf(xr, twi, fmaf( xi, twr, ai));
        float nr = fmaf(twr, cs, -twi * sn);
        twi = fmaf(twr, sn, twi * cs);
        twr = nr;
    }
    out[base + k] = sqrtf(ar*ar + ai*ai) * (1.0f/16384.0f);
}

// ---------------------------------------------------------------------------
// Row-wise L2 norm reciprocals (complex / real)
__global__ void k_norms_c(const float* __restrict__ Xr, const float* __restrict__ Xi,
                          float* __restrict__ recip) {
    int row = blockIdx.x; int tid = threadIdx.x;
    long base = (long)row * P;
    float s = 0.f;
    for (int n = tid; n < P; n += 256) {
        float r = Xr[base+n], i = Xi[base+n];
        s = fmaf(r, r, fmaf(i, i, s));
    }
    __shared__ float red[256];
    red[tid] = s; __syncthreads();
    for (int st = 128; st > 0; st >>= 1) {
        if (tid < st) red[tid] += red[tid+st];
        __syncthreads();
    }
    if (tid == 0) recip[row] = 1.0f / fmaxf(sqrtf(red[0]), 1e-12f);
}

__global__ void k_norms_r(const float* __restrict__ X, float* __restrict__ recip) {
    int row = blockIdx.x; int tid = threadIdx.x;
    long base = (long)row * P;
    float s = 0.f;
    for (int n = tid; n < P; n += 256) { float v = X[base+n]; s = fmaf(v, v, s); }
    __shared__ float red[256];
    red[tid] = s; __syncthreads();
    for (int st = 128; st > 0; st >>= 1) {
        if (tid < st) red[tid] += red[tid+st];
        __syncthreads();
    }
    if (tid == 0) recip[row] = 1.0f / fmaxf(sqrtf(red[0]), 1e-12f);
}

// ---------------------------------------------------------------------------
// Complex Gram partials: G[c][d] = sum_n qf[c][n]*qf[d][n] (NOT conjugated)
__global__ void k_gram_c(const float* __restrict__ Xr, const float* __restrict__ Xi,
                         float* __restrict__ gramP) {
    int bh = blockIdx.x >> 3, ck = blockIdx.x & 7;
    int tid = threadIdx.x; int c = tid >> 4, d = tid & 15;
    long bc = ((long)bh*16 + c) * P;
    long bd = ((long)bh*16 + d) * P;
    int n0 = ck * 2048;
    float ar = 0.f, ai = 0.f;
    for (int n = n0; n < n0 + 2048; ++n) {
        float qr = Xr[bc+n], qi = Xi[bc+n];
        float rr = Xr[bd+n], ri = Xi[bd+n];
        ar = fmaf(qr, rr, fmaf(-qi, ri, ar));
        ai = fmaf(qr, ri, fmaf( qi, rr, ai));
    }
    long o = ((long)(bh*8 + ck)*256 + tid)*2;
    gramP[o] = ar; gramP[o+1] = ai;
}

// ---------------------------------------------------------------------------
// attn_f: normalize, *temp, split softmax over d, then IDFT-16 over c (1/16 folded)
__global__ void k_attn_f(const float* __restrict__ gramP, const float* __restrict__ recip,
                         const float* __restrict__ tempf, float* __restrict__ attn2) {
    int bh = blockIdx.x; int tid = threadIdx.x;
    int c = tid >> 4, d = tid & 15;
    int hh = bh & 7;
    float gr = 0.f, gi = 0.f;
    for (int ck = 0; ck < 8; ++ck) {
        long o = ((long)(bh*8+ck)*256 + tid)*2;
        gr += gramP[o]; gi += gramP[o+1];
    }
    float sc = recip[bh*16+c] * recip[bh*16+d] * tempf[hh];
    float vr = gr * sc, vi = gi * sc;
    float mr = vr, mi = vi;
    for (int off = 8; off >= 1; off >>= 1) {
        mr = fmaxf(mr, __shfl_xor(mr, off));
        mi = fmaxf(mi, __shfl_xor(mi, off));
    }
    float er = expf(vr - mr), ei = expf(vi - mi);
    float ssr = er, ssi = ei;
    for (int off = 8; off >= 1; off >>= 1) {
        ssr += __shfl_xor(ssr, off);
        ssi += __shfl_xor(ssi, off);
    }
    float arv = er / ssr, aiv = ei / ssi;
    __shared__ float sR[256], sI[256];
    __shared__ float2 t16[16];
    sR[tid] = arv; sI[tid] = aiv;
    if (tid < 16) {
        float a = PI2F() * (float)tid / 16.0f;
        t16[tid] = make_float2(cosf(a), sinf(a));
    }
    __syncthreads();
    float ar2 = 0.f, ai2 = 0.f;
    #pragma unroll
    for (int cc = 0; cc < 16; ++cc) {
        float2 t = t16[(cc*c) & 15];
        float xr = sR[cc*16 + d], xi = sI[cc*16 + d];
        ar2 = fmaf(xr, t.x, fmaf(-xi, t.y, ar2));
        ai2 = fmaf(xr, t.y, fmaf( xi, t.x, ai2));
    }
    long o = ((long)bh*256 + tid)*2;
    attn2[o]   = ar2 * (1.0f/16.0f);
    attn2[o+1] = ai2 * (1.0f/16.0f);
}

// ---------------------------------------------------------------------------
// Y[c][n] = sum_d attn2[c][d] * qf[d][n]   (complex)
__global__ void k_yf(const float* __restrict__ attn2, const float* __restrict__ Xr,
                     const float* __restrict__ Xi, float* __restrict__ Yr,
                     float* __restrict__ Yi) {
    int bh = blockIdx.x >> 6;
    int nb = blockIdx.x & 63;
    int tid = threadIdx.x;
    __shared__ float aR[256], aI[256];
    { long o = ((long)bh*256 + tid)*2; aR[tid] = attn2[o]; aI[tid] = attn2[o+1]; }
    __syncthreads();
    long n = (long)nb*256 + tid;
    long rowb = (long)bh*16;
    float qr[16], qi[16];
    #pragma unroll
    for (int dd = 0; dd < 16; ++dd) {
        qr[dd] = Xr[(rowb+dd)*P + n];
        qi[dd] = Xi[(rowb+dd)*P + n];
    }
    for (int cc = 0; cc < 16; ++cc) {
        float ar = 0.f, ai = 0.f;
        #pragma unroll
        for (int dd = 0; dd < 16; ++dd) {
            float tr = aR[cc*16+dd], ti = aI[cc*16+dd];
            ar = fmaf(tr, qr[dd], fmaf(-ti, qi[dd], ar));
            ai = fmaf(tr, qi[dd], fmaf( ti, qr[dd], ai));
        }
        Yr[(rowb+cc)*P + n] = ar;
        Yi[(rowb+cc)*P + n] = ai;
    }
}

// ---------------------------------------------------------------------------
// Length-16384 IFFT pass 2 + abs. B1 (from k_dft_cols<+1>) holds B1[k2][n1] at
// base + k2*128 + n1. Lane owns k with k&127 == lane.
__global__ void k_pass2_abs(const float* __restrict__ B1r, const float* __restrict__ B1i,
                            float* __restrict__ out) {
    int row = blockIdx.x >> 3;
    int kb  = blockIdx.x & 7;
    int lane = threadIdx.x;          // 128 threads
    long base = (long)row * P;
    float accR[16], accI[16], twR[16], twI[16], stR[16], stI[16];
    #pragma unroll
    for (int j = 0; j < 16; ++j) {
        accR[j] = 0.f; accI[j] = 0.f; twR[j] = 1.f; twI[j] = 0.f;
        int k = kb*2048 + j*128 + lane;
        float a = PI2F() * (float)k / 16384.0f;
        stR[j] = cosf(a); stI[j] = sinf(a);
    }
    const float* pr = B1r + base + (long)lane*128;
    const float* pi = B1i + base + (long)lane*128;
    for (int n1 = 0; n1 < 128; n1 += 4) {
        float4 vr = *(const float4*)(pr + n1);
        float4 vi = *(const float4*)(pi + n1);
        float brs[4] = {vr.x, vr.y, vr.z, vr.w};
        float bis[4] = {vi.x, vi.y, vi.z, vi.w};
        #pragma unroll
        for (int q = 0; q < 4; ++q) {
            float br = brs[q], bi = bis[q];
            #pragma unroll
            for (int j = 0; j < 16; ++j) {
                accR[j] = fmaf(br, twR[j], fmaf(-bi, twI[j], accR[j]));
                accI[j] = fmaf(br, twI[j], fmaf( bi, twR[j], accI[j]));
                float nr = fmaf(twR[j], stR[j], -twI[j]*stI[j]);
                twI[j] = fmaf(twR[j], stI[j], twI[j]*stR[j]);
                twR[j] = nr;
            }
        }
    }
    #pragma unroll
    for (int j = 0; j < 16; ++j) {
        int k = kb*2048 + j*128 + lane;
        out[base + k] = sqrtf(accR[j]*accR[j] + accI[j]*accI[j]) * (1.0f/16384.0f);
    }
}

// ---------------------------------------------------------------------------
// q/k/v 1x1 convs (one launch; which = q/k/v). 16 outch per thread.
__global__ void k_conv1x1qkv(const float* __restrict__ x,
                             const float* __restrict__ Wq, const float* __restrict__ bq,
                             const float* __restrict__ Wk, const float* __restrict__ bk,
                             const float* __restrict__ Wv, const float* __restrict__ bv,
                             float* __restrict__ Oq, float* __restrict__ Ok,
                             float* __restrict__ Ov) {
    int pc = blockIdx.x;                 // 64
    int og = blockIdx.y & 7, which = blockIdx.y >> 3;   // y: 24
    int b = blockIdx.z;                  // chunk-local batch
    const float* W    = which == 0 ? Wq : which == 1 ? Wk : Wv;
    const float* bias = which == 0 ? bq : which == 1 ? bk : bv;
    float* O          = which == 0 ? Oq : which == 1 ? Ok : Ov;
    long p = (long)pc*256 + threadIdx.x;
    float acc[16];
    #pragma unroll
    for (int j = 0; j < 16; ++j) acc[j] = bias[og*16+j];
    const float* xb = x + (long)b*C*P + p;
    for (int c = 0; c < 128; ++c) {
        float xv = xb[(long)c*P];
        #pragma unroll
        for (int j = 0; j < 16; ++j)
            acc[j] = fmaf(W[(og*16+j)*128 + c], xv, acc[j]);
    }
    long ob = (long)b*C*P + (long)(og*16)*P + p;
    #pragma unroll
    for (int j = 0; j < 16; ++j) O[ob + (long)j*P] = acc[j];
}

// ---------------------------------------------------------------------------
// Grouped conv: out ch g<64 = 3x3(pad1) over in ch (2g,2g+1); g>=64 = 5x5(pad2)
__global__ void k_gconv(const float* __restrict__ in, const float* __restrict__ w3,
                        const float* __restrict__ w5, float* __restrict__ out) {
    int bid = blockIdx.x;
    int pc = bid & 63;
    int ch = (bid >> 6) & 127;
    int b  = bid >> 13;                  // chunk-local batch
    int p = pc*256 + threadIdx.x;
    int h = p >> 7, w = p & 127;
    float acc = 0.f;
    if (ch < 64) {
        int g = ch;
        const float* ib = in + ((long)b*C + 2*g)*P;
        #pragma unroll
        for (int ic = 0; ic < 2; ++ic) {
            const float* wp = w3 + (g*2 + ic)*9;
            #pragma unroll
            for (int ky = 0; ky < 3; ++ky) {
                int h2 = h + ky - 1;
                if (h2 < 0 || h2 > 127) continue;
                #pragma unroll
                for (int kx = 0; kx < 3; ++kx) {
                    int w2_ = w + kx - 1;
                    if (w2_ < 0 || w2_ > 127) continue;
                    acc = fmaf(wp[ky*3+kx], ib[(long)ic*P + h2*128 + w2_], acc);
                }
            }
        }
    } else {
        int g = ch - 64;
        const float* ib = in + ((long)b*C + 2*g)*P;
        #pragma unroll
        for (int ic = 0; ic < 2; ++ic) {
            const float* wp = w5 + (g*2 + ic)*25;
            #pragma unroll
            for (int ky = 0; ky < 5; ++ky) {
                int h2 = h + ky - 2;
                if (h2 < 0 || h2 > 127) continue;
                #pragma unroll
                for (int kx = 0; kx < 5; ++kx) {
                    int w2_ = w + kx - 2;
                    if (w2_ < 0 || w2_ > 127) continue;
                    acc = fmaf(wp[ky*5+kx], ib[(long)ic*P + h2*128 + w2_], acc);
                }
            }
        }
    }
    out[((long)b*C + ch)*P + p] = acc;
}

// ---------------------------------------------------------------------------
// Real Gram partials for spatial attention
__global__ void k_gram_r(const float* __restrict__ Q, const float* __restrict__ K,
                         float* __restrict__ gramP) {
    int bh = blockIdx.x >> 3, ck = blockIdx.x & 7;
    int tid = threadIdx.x; int c = tid >> 4, d = tid & 15;
    long bc = ((long)bh*16 + c) * P;
    long bd = ((long)bh*16 + d) * P;
    int n0 = ck*2048;
    float a = 0.f;
    for (int n = n0; n < n0+2048; ++n)
        a = fmaf(Q[bc+n], K[bd+n], a);
    gramP[(long)(bh*8+ck)*256 + tid] = a;
}

__global__ void k_attn_s(const float* __restrict__ gramP, const float* __restrict__ rq,
                         const float* __restrict__ rk, const float* __restrict__ temps,
                         float* __restrict__ attn) {
    int bh = blockIdx.x; int tid = threadIdx.x;
    int c = tid >> 4, d = tid & 15;
    float g = 0.f;
    for (int ck = 0; ck < 8; ++ck) g += gramP[(long)(bh*8+ck)*256 + tid];
    g *= rq[bh*16+c] * rk[bh*16+d] * temps[bh & 7];
    float m = g;
    for (int off = 8; off >= 1; off >>= 1) m = fmaxf(m, __shfl_xor(m, off));
    float e = expf(g - m);
    float s = e;
    for (int off = 8; off >= 1; off >>= 1) s += __shfl_xor(s, off);
    attn[(long)bh*256 + tid] = e / s;
}

__global__ void k_outs(const float* __restrict__ attn, const float* __restrict__ V,
                       float* __restrict__ out) {
    int bh = blockIdx.x >> 6, nb = blockIdx.x & 63;
    int tid = threadIdx.x;
    __shared__ float aS[256];
    aS[tid] = attn[(long)bh*256 + tid];
    __syncthreads();
    long n = (long)nb*256 + tid;
    long rowb = (long)bh*16;
    float vv[16];
    #pragma unroll
    for (int dd = 0; dd < 16; ++dd) vv[dd] = V[(rowb+dd)*P + n];
    for (int cc = 0; cc < 16; ++cc) {
        float a = 0.f;
        #pragma unroll
        for (int dd = 0; dd < 16; ++dd) a = fmaf(aS[cc*16+dd], vv[dd], a);
        out[(rowb+cc)*P + n] = a;
    }
}

// ---------------------------------------------------------------------------
// Final fused projection: out = projf([OF;OFL]) + projs([OS;OSL]), no bias
__global__ void k_finalproj(const float* __restrict__ OF, const float* __restrict__ OFL,
                            const float* __restrict__ OS, const float* __restrict__ OSL,
                            const float* __restrict__ Wf, const float* __restrict__ Ws,
                            float* __restrict__ out) {
    int pc = blockIdx.x, og = blockIdx.y, b = blockIdx.z;   // 64, 8, NB
    long p = (long)pc*256 + threadIdx.x;
    float acc[16];
    #pragma unroll
    for (int j = 0; j < 16; ++j) acc[j] = 0.f;
    long xb = (long)b*C*P + p;
    for (int c = 0; c < 128; ++c) {
        float v0 = OF [xb + (long)c*P];
        float v1 = OFL[xb + (long)c*P];
        float v2 = OS [xb + (long)c*P];
        float v3 = OSL[xb + (long)c*P];
        #pragma unroll
        for (int j = 0; j < 16; ++j) {
            int o = og*16 + j;
            acc[j] = fmaf(Wf[o*256 + c], v0,
                     fmaf(Wf[o*256 + 128 + c], v1,
                     fmaf(Ws[o*256 + c], v2,
                     fmaf(Ws[o*256 + 128 + c], v3, acc[j]))));
        }
    }
    long ob = (long)b*C*P + (long)(og*16)*P + p;
    #pragma unroll
    for (int j = 0; j < 16; ++j) out[ob + (long)j*P] = acc[j];
}

// ---------------------------------------------------------------------------
static long ws_need_bytes(int bc) {
    long pb = (long)bc * C * P;          // one big buffer (floats)
    long extras = (long)bc*8*P           // Mg
                + (long)bc*128*3         // normF, recQ, recK
                + (long)bc*8*8*256*2     // gramC
                + (long)bc*8*256*2       // attn2
                + (long)bc*8*8*256       // gramS
                + (long)bc*8*256;        // attnS
    return (6*pb + extras) * 4;
}

extern "C" void kernel_launch(void* const* d_in, const int* in_sizes, int n_in,
                              void* d_out, int out_size, void* d_ws, size_t ws_size,
                              hipStream_t stream) {
    const float* x      = (const float*)d_in[0];
    const float* temp_f = (const float*)d_in[1];
    const float* w1     = (const float*)d_in[2];
    const float* b1     = (const float*)d_in[3];
    const float* bng    = (const float*)d_in[4];
    const float* bnb    = (const float*)d_in[5];
    const float* bnm    = (const float*)d_in[6];
    const float* bnv    = (const float*)d_in[7];
    const float* w2     = (const float*)d_in[8];
    const float* b2     = (const float*)d_in[9];
    const float* projf  = (const float*)d_in[10];
    const float* temp_s = (const float*)d_in[11];
    const float* q1w = (const float*)d_in[12]; const float* q1b = (const float*)d_in[13];
    const float* k1w = (const float*)d_in[14]; const float* k1b = (const float*)d_in[15];
    const float* v1w = (const float*)d_in[16]; const float* v1b = (const float*)d_in[17];
    const float* q3w = (const float*)d_in[18]; const float* q5w = (const float*)d_in[19];
    const float* k3w = (const float*)d_in[20]; const float* k5w = (const float*)d_in[21];
    const float* v3w = (const float*)d_in[22]; const float* v5w = (const float*)d_in[23];
    const float* c3w = (const float*)d_in[24]; const float* c5w = (const float*)d_in[25];
    const float* projs  = (const float*)d_in[26];
    float* out = (float*)d_out;
    float* ws = (float*)d_ws;

    // Pick the largest batch-chunk that fits the workspace (8 -> ~410MB, 1 -> ~51MB)
    int bc = 1;
    if ((long)ws_size >= ws_need_bytes(8)) bc = 8;
    else if ((long)ws_size >= ws_need_bytes(4)) bc = 4;
    else if ((long)ws_size >= ws_need_bytes(2)) bc = 2;
    const int NB = bc;
    const long pb = (long)bc * C * P;

    float* t0 = ws + 0*pb;
    float* t1 = ws + 1*pb;
    float* t2 = ws + 2*pb;
    float* t3 = ws + 3*pb;
    float* t4 = ws + 4*pb;
    float* t5 = ws + 5*pb;
    float* Mg    = ws + 6*pb;                       // bc*8*P
    float* normF = Mg + (long)bc*8*P;               // bc*128
    float* recQ  = normF + (long)bc*128;
    float* recK  = recQ + (long)bc*128;
    float* gramC = recK + (long)bc*128;             // bc*8*8*256*2
    float* attn2 = gramC + (long)bc*8*8*256*2;      // bc*8*256*2
    float* gramS = attn2 + (long)bc*8*256*2;        // bc*8*8*256
    float* attnS = gramS + (long)bc*8*8*256;        // bc*8*256

    for (int ckk = 0; ckk < 8/bc; ++ckk) {
        const float* xc = x + (long)ckk * bc * C * P;
        float* outc = out + (long)ckk * bc * C * P;

        // ================= frequency branch =================
        k_dft_rows_fwd<<<NB*C*HH, 128, 0, stream>>>(xc, t0, t1);
        k_dft_cols<-1><<<NB*C*8, 128, 0, stream>>>(t0, t1, t2, t3);      // XF=(t2,t3)
        k_gate_mid<<<(NB*P)/256, 256, 0, stream>>>(t2, w1, b1, bng, bnb, bnm, bnv, Mg);
        k_gate_idft_h<<<NB*C*8, 128, 0, stream>>>(t2, t3, Mg, w2, b2, t0, t1);
        k_idft_rows_abs<<<NB*C*HH, 128, 0, stream>>>(t0, t1, t4);        // OFL=t4
        k_norms_c<<<NB*C, 256, 0, stream>>>(t2, t3, normF);
        k_gram_c<<<NB*8*8, 256, 0, stream>>>(t2, t3, gramC);
        k_attn_f<<<NB*8, 256, 0, stream>>>(gramC, normF, temp_f, attn2);
        k_yf<<<NB*8*64, 256, 0, stream>>>(attn2, t2, t3, t0, t1);        // Y=(t0,t1)
        k_dft_cols<+1><<<NB*C*8, 128, 0, stream>>>(t0, t1, t2, t3);      // B1=(t2,t3)
        k_pass2_abs<<<NB*C*8, 128, 0, stream>>>(t2, t3, t0);             // OF=t0

        // ================= spatial branch =================
        k_conv1x1qkv<<<dim3(64, 24, NB), 256, 0, stream>>>(xc, q1w, q1b, k1w, k1b,
                                                           v1w, v1b, t1, t2, t3);
        k_gconv<<<NB*128*64, 256, 0, stream>>>(t1, q3w, q5w, t5);   // QS=t5
        k_gconv<<<NB*128*64, 256, 0, stream>>>(t2, k3w, k5w, t1);   // KS=t1
        k_gconv<<<NB*128*64, 256, 0, stream>>>(t3, v3w, v5w, t2);   // VS=t2
        k_gconv<<<NB*128*64, 256, 0, stream>>>(xc, c3w, c5w, t3);   // OSL=t3
        k_norms_r<<<NB*C, 256, 0, stream>>>(t5, recQ);
        k_norms_r<<<NB*C, 256, 0, stream>>>(t1, recK);
        k_gram_r<<<NB*8*8, 256, 0, stream>>>(t5, t1, gramS);
        k_attn_s<<<NB*8, 256, 0, stream>>>(gramS, recQ, recK, temp_s, attnS);
        k_outs<<<NB*8*64, 256, 0, stream>>>(attnS, t2, t5);         // OS=t5

        // ================= fused projections + add =================
        k_finalproj<<<dim3(64, 8, NB), 256, 0, stream>>>(t0, t4, t5, t3,
                                                         projf, projs, outc);
    }
}

// Round 3
// 5193.147 us; speedup vs baseline: 1.3345x; 1.3345x over previous
//
#include <hip/hip_runtime.h>
#include <math.h>

#define B 8
#define C 128
#define HEADS 8
#define HD 16
#define HH 128
#define WW 128
#define P 16384          // HH*WW

static __device__ __forceinline__ float PI2F() { return 6.28318530717958647692f; }

// ---------------------------------------------------------------------------
// Forward DFT-128 along contiguous (w) axis; real input. One block per row.
__global__ void k_dft_rows_fwd(const float* __restrict__ x,
                               float* __restrict__ outR, float* __restrict__ outI) {
    int row = blockIdx.x;
    int k = threadIdx.x;             // 0..127
    long base = (long)row * 128;
    float a = -PI2F() * (float)k / 128.0f;
    float cs = cosf(a), sn = sinf(a);
    float twr = 1.f, twi = 0.f, ar = 0.f, ai = 0.f;
    for (int w = 0; w < 128; ++w) {
        float xv = x[base + w];      // lane-uniform -> scalar load
        ar = fmaf(xv, twr, ar);
        ai = fmaf(xv, twi, ai);
        float nr = fmaf(twr, cs, -twi * sn);
        twi = fmaf(twr, sn, twi * cs);
        twr = nr;
    }
    outR[base + k] = ar;
    outI[base + k] = ai;
}

// ---------------------------------------------------------------------------
// DFT-128 along the strided (h) axis, LDS-staged, split-2 per image.
// Block = 512 threads; blockIdx = img*2 + half. Thread (kg=tid>>7, lane=tid&127)
// computes k = half*64 + kg*16 + j (j=0..15) for its lane column.
template<int SIGN>
__global__ __launch_bounds__(512) void k_dft_cols_x1(
        const float* __restrict__ inR, const float* __restrict__ inI,
        float* __restrict__ outR, float* __restrict__ outI) {
    __shared__ float2 tw[128];
    __shared__ float sR[16][128], sI[16][128];
    int img = blockIdx.x >> 1;
    int half = blockIdx.x & 1;
    int tid = threadIdx.x;
    int lane = tid & 127, kg = tid >> 7;     // kg 0..3
    int kbase = half*64 + kg*16;
    if (tid < 128) {
        float a = PI2F() * (float)tid / 128.0f;
        tw[tid] = make_float2(cosf(a), SIGN > 0 ? sinf(a) : -sinf(a));
    }
    long base = (long)img * P;
    float accR[16], accI[16];
    #pragma unroll
    for (int j = 0; j < 16; ++j) { accR[j] = 0.f; accI[j] = 0.f; }
    for (int h0 = 0; h0 < 128; h0 += 16) {
        __syncthreads();
        #pragma unroll
        for (int t = 0; t < 4; ++t) {
            int idx = tid + t*512;           // 0..2047
            int hh = idx >> 7, ln = idx & 127;
            sR[hh][ln] = inR[base + (h0+hh)*128 + ln];
            sI[hh][ln] = inI[base + (h0+hh)*128 + ln];
        }
        __syncthreads();
        for (int hh = 0; hh < 16; ++hh) {
            float xr = sR[hh][lane], xi = sI[hh][lane];
            int h = h0 + hh;
            #pragma unroll
            for (int j = 0; j < 16; ++j) {
                int k = kbase + j;
                float2 t = tw[(h*k) & 127];   // wave-uniform broadcast
                accR[j] = fmaf(xr, t.x, fmaf(-xi, t.y, accR[j]));
                accI[j] = fmaf(xr, t.y, fmaf( xi, t.x, accI[j]));
            }
        }
    }
    #pragma unroll
    for (int j = 0; j < 16; ++j) {
        int k = kbase + j;
        outR[base + k*128 + lane] = accR[j];
        outI[base + k*128 + lane] = accI[j];
    }
}

// ---------------------------------------------------------------------------
// SE gate stage 1: M[b,j,p] = relu(bn(b1[j] + sum_c W1[j][c]*XFr[b,c,p]))
__global__ void k_gate_mid(const float* __restrict__ XFr, const float* __restrict__ w1,
                           const float* __restrict__ b1, const float* __restrict__ gamma,
                           const float* __restrict__ beta, const float* __restrict__ mean,
                           const float* __restrict__ var, float* __restrict__ M) {
    __shared__ float w1s[8*128];
    int tid = threadIdx.x;
    for (int i = tid; i < 1024; i += 256) w1s[i] = w1[i];
    __syncthreads();
    long idx = (long)blockIdx.x * 256 + tid;
    int b = (int)(idx >> 14);
    int p = (int)(idx & 16383);
    float acc[8];
    #pragma unroll
    for (int j = 0; j < 8; ++j) acc[j] = b1[j];
    const float* xb = XFr + (long)b * C * P + p;
    for (int c = 0; c < 128; ++c) {
        float xv = xb[(long)c * P];
        #pragma unroll
        for (int j = 0; j < 8; ++j) acc[j] = fmaf(w1s[j*128 + c], xv, acc[j]);
    }
    #pragma unroll
    for (int j = 0; j < 8; ++j) {
        float v = (acc[j] - mean[j]) * rsqrtf(var[j] + 1e-5f) * gamma[j] + beta[j];
        M[((long)b*8 + j)*P + p] = fmaxf(v, 0.f);
    }
}

// ---------------------------------------------------------------------------
// Gate stage 2 fused with IDFT-128 along h, LDS-staged split-2.
// Staging computes g = sigmoid(W2*M + b2) and stores g*XF into LDS.
__global__ __launch_bounds__(512) void k_gate_idft_x1(
        const float* __restrict__ XFr, const float* __restrict__ XFi,
        const float* __restrict__ Mg, const float* __restrict__ w2,
        const float* __restrict__ b2,
        float* __restrict__ outR, float* __restrict__ outI) {
    __shared__ float2 tw[128];
    __shared__ float sR[16][128], sI[16][128];
    int img = blockIdx.x >> 1;
    int half = blockIdx.x & 1;
    int tid = threadIdx.x;
    int lane = tid & 127, kg = tid >> 7;
    int kbase = half*64 + kg*16;
    if (tid < 128) {
        float a = PI2F() * (float)tid / 128.0f;
        tw[tid] = make_float2(cosf(a), sinf(a));    // sign +
    }
    int b = img >> 7, c = img & 127;
    float w2r[8];
    #pragma unroll
    for (int j = 0; j < 8; ++j) w2r[j] = w2[c*8 + j];
    float b2c = b2[c];
    long base = (long)img * P;
    const float* mb = Mg + (long)b*8*P;
    float accR[16], accI[16];
    #pragma unroll
    for (int j = 0; j < 16; ++j) { accR[j] = 0.f; accI[j] = 0.f; }
    for (int h0 = 0; h0 < 128; h0 += 16) {
        __syncthreads();
        #pragma unroll
        for (int t = 0; t < 4; ++t) {
            int idx = tid + t*512;
            int hh = idx >> 7, ln = idx & 127;
            int off = (h0+hh)*128 + ln;
            float z = b2c;
            #pragma unroll
            for (int j = 0; j < 8; ++j) z = fmaf(w2r[j], mb[(long)j*P + off], z);
            float g = 1.0f / (1.0f + expf(-z));
            sR[hh][ln] = g * XFr[base + off];
            sI[hh][ln] = g * XFi[base + off];
        }
        __syncthreads();
        for (int hh = 0; hh < 16; ++hh) {
            float xr = sR[hh][lane], xi = sI[hh][lane];
            int h = h0 + hh;
            #pragma unroll
            for (int j = 0; j < 16; ++j) {
                int k = kbase + j;
                float2 t = tw[(h*k) & 127];
                accR[j] = fmaf(xr, t.x, fmaf(-xi, t.y, accR[j]));
                accI[j] = fmaf(xr, t.y, fmaf( xi, t.x, accI[j]));
            }
        }
    }
    #pragma unroll
    for (int j = 0; j < 16; ++j) {
        int k = kbase + j;
        outR[base + k*128 + lane] = accR[j];
        outI[base + k*128 + lane] = accI[j];
    }
}

// ---------------------------------------------------------------------------
// IDFT-128 along contiguous axis + 1/16384 scale + abs
__global__ void k_idft_rows_abs(const float* __restrict__ inR, const float* __restrict__ inI,
                                float* __restrict__ out) {
    int row = blockIdx.x;
    int k = threadIdx.x;
    long base = (long)row * 128;
    float a = PI2F() * (float)k / 128.0f;
    float cs = cosf(a), sn = sinf(a);
    float twr = 1.f, twi = 0.f, ar = 0.f, ai = 0.f;
    for (int w = 0; w < 128; ++w) {
        float xr = inR[base + w], xi = inI[base + w];   // lane-uniform
        ar = fmaf(xr, twr, fmaf(-xi, twi, ar));
        ai = fmaf(xr, twi, fmaf( xi, twr, ai));
        float nr = fmaf(twr, cs, -twi * sn);
        twi = fmaf(twr, sn, twi * cs);
        twr = nr;
    }
    out[base + k] = sqrtf(ar*ar + ai*ai) * (1.0f/16384.0f);
}

// ---------------------------------------------------------------------------
// Row-wise L2 norm reciprocals (complex / real)
__global__ void k_norms_c(const float* __restrict__ Xr, const float* __restrict__ Xi,
                          float* __restrict__ recip) {
    int row = blockIdx.x; int tid = threadIdx.x;
    long base = (long)row * P;
    float s = 0.f;
    for (int n = tid; n < P; n += 256) {
        float r = Xr[base+n], i = Xi[base+n];
        s = fmaf(r, r, fmaf(i, i, s));
    }
    __shared__ float red[256];
    red[tid] = s; __syncthreads();
    for (int st = 128; st > 0; st >>= 1) {
        if (tid < st) red[tid] += red[tid+st];
        __syncthreads();
    }
    if (tid == 0) recip[row] = 1.0f / fmaxf(sqrtf(red[0]), 1e-12f);
}

__global__ void k_norms_r(const float* __restrict__ X, float* __restrict__ recip) {
    int row = blockIdx.x; int tid = threadIdx.x;
    long base = (long)row * P;
    float s = 0.f;
    for (int n = tid; n < P; n += 256) { float v = X[base+n]; s = fmaf(v, v, s); }
    __shared__ float red[256];
    red[tid] = s; __syncthreads();
    for (int st = 128; st > 0; st >>= 1) {
        if (tid < st) red[tid] += red[tid+st];
        __syncthreads();
    }
    if (tid == 0) recip[row] = 1.0f / fmaxf(sqrtf(red[0]), 1e-12f);
}

// ---------------------------------------------------------------------------
// Complex Gram partials: G[c][d] = sum_n qf[c][n]*qf[d][n] (NOT conjugated)
__global__ void k_gram_c(const float* __restrict__ Xr, const float* __restrict__ Xi,
                         float* __restrict__ gramP) {
    int bh = blockIdx.x >> 3, ck = blockIdx.x & 7;
    int tid = threadIdx.x; int c = tid >> 4, d = tid & 15;
    long bc = ((long)bh*16 + c) * P;
    long bd = ((long)bh*16 + d) * P;
    int n0 = ck * 2048;
    float ar = 0.f, ai = 0.f;
    for (int n = n0; n < n0 + 2048; ++n) {
        float qr = Xr[bc+n], qi = Xi[bc+n];
        float rr = Xr[bd+n], ri = Xi[bd+n];
        ar = fmaf(qr, rr, fmaf(-qi, ri, ar));
        ai = fmaf(qr, ri, fmaf( qi, rr, ai));
    }
    long o = ((long)(bh*8 + ck)*256 + tid)*2;
    gramP[o] = ar; gramP[o+1] = ai;
}

// ---------------------------------------------------------------------------
// attn_f: normalize, *temp, split softmax over d, then IDFT-16 over c (1/16 folded)
__global__ void k_attn_f(const float* __restrict__ gramP, const float* __restrict__ recip,
                         const float* __restrict__ tempf, float* __restrict__ attn2) {
    int bh = blockIdx.x; int tid = threadIdx.x;
    int c = tid >> 4, d = tid & 15;
    int hh = bh & 7;
    float gr = 0.f, gi = 0.f;
    for (int ck = 0; ck < 8; ++ck) {
        long o = ((long)(bh*8+ck)*256 + tid)*2;
        gr += gramP[o]; gi += gramP[o+1];
    }
    float sc = recip[bh*16+c] * recip[bh*16+d] * tempf[hh];
    float vr = gr * sc, vi = gi * sc;
    float mr = vr, mi = vi;
    for (int off = 8; off >= 1; off >>= 1) {
        mr = fmaxf(mr, __shfl_xor(mr, off));
        mi = fmaxf(mi, __shfl_xor(mi, off));
    }
    float er = expf(vr - mr), ei = expf(vi - mi);
    float ssr = er, ssi = ei;
    for (int off = 8; off >= 1; off >>= 1) {
        ssr += __shfl_xor(ssr, off);
        ssi += __shfl_xor(ssi, off);
    }
    float arv = er / ssr, aiv = ei / ssi;
    __shared__ float sR[256], sI[256];
    __shared__ float2 t16[16];
    sR[tid] = arv; sI[tid] = aiv;
    if (tid < 16) {
        float a = PI2F() * (float)tid / 16.0f;
        t16[tid] = make_float2(cosf(a), sinf(a));
    }
    __syncthreads();
    float ar2 = 0.f, ai2 = 0.f;
    #pragma unroll
    for (int cc = 0; cc < 16; ++cc) {
        float2 t = t16[(cc*c) & 15];
        float xr = sR[cc*16 + d], xi = sI[cc*16 + d];
        ar2 = fmaf(xr, t.x, fmaf(-xi, t.y, ar2));
        ai2 = fmaf(xr, t.y, fmaf( xi, t.x, ai2));
    }
    long o = ((long)bh*256 + tid)*2;
    attn2[o]   = ar2 * (1.0f/16.0f);
    attn2[o+1] = ai2 * (1.0f/16.0f);
}

// ---------------------------------------------------------------------------
// Y[c][n] = sum_d attn2[c][d] * qf[d][n]   (complex)
__global__ void k_yf(const float* __restrict__ attn2, const float* __restrict__ Xr,
                     const float* __restrict__ Xi, float* __restrict__ Yr,
                     float* __restrict__ Yi) {
    int bh = blockIdx.x >> 6;
    int nb = blockIdx.x & 63;
    int tid = threadIdx.x;
    __shared__ float aR[256], aI[256];
    { long o = ((long)bh*256 + tid)*2; aR[tid] = attn2[o]; aI[tid] = attn2[o+1]; }
    __syncthreads();
    long n = (long)nb*256 + tid;
    long rowb = (long)bh*16;
    float qr[16], qi[16];
    #pragma unroll
    for (int dd = 0; dd < 16; ++dd) {
        qr[dd] = Xr[(rowb+dd)*P + n];
        qi[dd] = Xi[(rowb+dd)*P + n];
    }
    for (int cc = 0; cc < 16; ++cc) {
        float ar = 0.f, ai = 0.f;
        #pragma unroll
        for (int dd = 0; dd < 16; ++dd) {
            float tr = aR[cc*16+dd], ti = aI[cc*16+dd];
            ar = fmaf(tr, qr[dd], fmaf(-ti, qi[dd], ar));
            ai = fmaf(tr, qi[dd], fmaf( ti, qr[dd], ai));
        }
        Yr[(rowb+cc)*P + n] = ar;
        Yi[(rowb+cc)*P + n] = ai;
    }
}

// ---------------------------------------------------------------------------
// Length-16384 IFFT pass 2 + abs, LDS version.
// Z[k] = (1/16384) sum_n1 B1[k&127][n1] e^{2pi i n1 k/16384}, k = k1*128 + k2.
// Block owns k2 group of 16 (contiguous 8KB read); premultiplies twiddle into
// LDS; thread k1 accumulates with a per-thread rotation recurrence.
__global__ __launch_bounds__(128) void k_pass2x(const float* __restrict__ B1r,
                                                const float* __restrict__ B1i,
                                                float* __restrict__ out) {
    __shared__ float Dr[16][128], Di[16][128];
    int img = blockIdx.x >> 3;
    int k2g = blockIdx.x & 7;
    int tid = threadIdx.x;           // 128 threads, tid = k1
    long base = (long)img * P;
    const float* pr = B1r + base + (long)k2g*2048;
    const float* pi = B1i + base + (long)k2g*2048;
    #pragma unroll
    for (int t = 0; t < 16; ++t) {
        int idx = tid + t*128;       // 0..2047, coalesced
        int j = idx >> 7, n1 = idx & 127;
        float br = pr[idx], bi = pi[idx];
        float ang = (PI2F()/16384.0f) * (float)(n1 * (k2g*16 + j));
        float s, cz;
        __sincosf(ang, &s, &cz);
        Dr[j][n1] = br*cz - bi*s;
        Di[j][n1] = br*s + bi*cz;
    }
    __syncthreads();
    float sr, si;
    __sincosf(PI2F() * (float)tid / 128.0f, &si, &sr);   // step e^{2pi i k1/128}
    float wr = 1.f, wi = 0.f;
    float accR[16], accI[16];
    #pragma unroll
    for (int j = 0; j < 16; ++j) { accR[j] = 0.f; accI[j] = 0.f; }
    for (int n1 = 0; n1 < 128; ++n1) {
        #pragma unroll
        for (int j = 0; j < 16; ++j) {
            float dr = Dr[j][n1], di = Di[j][n1];     // wave-uniform broadcast
            accR[j] = fmaf(dr, wr, fmaf(-di, wi, accR[j]));
            accI[j] = fmaf(dr, wi, fmaf( di, wr, accI[j]));
        }
        float nr = fmaf(wr, sr, -wi*si);
        wi = fmaf(wr, si, wi*sr);
        wr = nr;
    }
    float4 v[4];
    #pragma unroll
    for (int j = 0; j < 16; ++j) {
        ((float*)v)[j] = sqrtf(accR[j]*accR[j] + accI[j]*accI[j]) * (1.0f/16384.0f);
    }
    float4* op = (float4*)(out + base + (long)tid*128 + k2g*16);
    #pragma unroll
    for (int q = 0; q < 4; ++q) op[q] = v[q];
}

// ---------------------------------------------------------------------------
// q/k/v 1x1 convs (one launch; which = q/k/v). 16 outch per thread.
__global__ void k_conv1x1qkv(const float* __restrict__ x,
                             const float* __restrict__ Wq, const float* __restrict__ bq,
                             const float* __restrict__ Wk, const float* __restrict__ bk,
                             const float* __restrict__ Wv, const float* __restrict__ bv,
                             float* __restrict__ Oq, float* __restrict__ Ok,
                             float* __restrict__ Ov) {
    int pc = blockIdx.x;                 // 64
    int og = blockIdx.y & 7, which = blockIdx.y >> 3;   // y: 24
    int b = blockIdx.z;
    const float* W    = which == 0 ? Wq : which == 1 ? Wk : Wv;
    const float* bias = which == 0 ? bq : which == 1 ? bk : bv;
    float* O          = which == 0 ? Oq : which == 1 ? Ok : Ov;
    long p = (long)pc*256 + threadIdx.x;
    float acc[16];
    #pragma unroll
    for (int j = 0; j < 16; ++j) acc[j] = bias[og*16+j];
    const float* xb = x + (long)b*C*P + p;
    for (int c = 0; c < 128; ++c) {
        float xv = xb[(long)c*P];
        #pragma unroll
        for (int j = 0; j < 16; ++j)
            acc[j] = fmaf(W[(og*16+j)*128 + c], xv, acc[j]);
    }
    long ob = (long)b*C*P + (long)(og*16)*P + p;
    #pragma unroll
    for (int j = 0; j < 16; ++j) O[ob + (long)j*P] = acc[j];
}

// ---------------------------------------------------------------------------
// Grouped conv: out ch g<64 = 3x3(pad1) over in ch (2g,2g+1); g>=64 = 5x5(pad2)
__global__ void k_gconv(const float* __restrict__ in, const float* __restrict__ w3,
                        const float* __restrict__ w5, float* __restrict__ out) {
    int bid = blockIdx.x;
    int pc = bid & 63;
    int ch = (bid >> 6) & 127;
    int b  = bid >> 13;
    int p = pc*256 + threadIdx.x;
    int h = p >> 7, w = p & 127;
    float acc = 0.f;
    if (ch < 64) {
        int g = ch;
        const float* ib = in + ((long)b*C + 2*g)*P;
        #pragma unroll
        for (int ic = 0; ic < 2; ++ic) {
            const float* wp = w3 + (g*2 + ic)*9;
            #pragma unroll
            for (int ky = 0; ky < 3; ++ky) {
                int h2 = h + ky - 1;
                if (h2 < 0 || h2 > 127) continue;
                #pragma unroll
                for (int kx = 0; kx < 3; ++kx) {
                    int w2_ = w + kx - 1;
                    if (w2_ < 0 || w2_ > 127) continue;
                    acc = fmaf(wp[ky*3+kx], ib[(long)ic*P + h2*128 + w2_], acc);
                }
            }
        }
    } else {
        int g = ch - 64;
        const float* ib = in + ((long)b*C + 2*g)*P;
        #pragma unroll
        for (int ic = 0; ic < 2; ++ic) {
            const float* wp = w5 + (g*2 + ic)*25;
            #pragma unroll
            for (int ky = 0; ky < 5; ++ky) {
                int h2 = h + ky - 2;
                if (h2 < 0 || h2 > 127) continue;
                #pragma unroll
                for (int kx = 0; kx < 5; ++kx) {
                    int w2_ = w + kx - 2;
                    if (w2_ < 0 || w2_ > 127) continue;
                    acc = fmaf(wp[ky*5+kx], ib[(long)ic*P + h2*128 + w2_], acc);
                }
            }
        }
    }
    out[((long)b*C + ch)*P + p] = acc;
}

// ---------------------------------------------------------------------------
// Real Gram partials for spatial attention
__global__ void k_gram_r(const float* __restrict__ Q, const float* __restrict__ K,
                         float* __restrict__ gramP) {
    int bh = blockIdx.x >> 3, ck = blockIdx.x & 7;
    int tid = threadIdx.x; int c = tid >> 4, d = tid & 15;
    long bc = ((long)bh*16 + c) * P;
    long bd = ((long)bh*16 + d) * P;
    int n0 = ck*2048;
    float a = 0.f;
    for (int n = n0; n < n0+2048; ++n)
        a = fmaf(Q[bc+n], K[bd+n], a);
    gramP[(long)(bh*8+ck)*256 + tid] = a;
}

__global__ void k_attn_s(const float* __restrict__ gramP, const float* __restrict__ rq,
                         const float* __restrict__ rk, const float* __restrict__ temps,
                         float* __restrict__ attn) {
    int bh = blockIdx.x; int tid = threadIdx.x;
    int c = tid >> 4, d = tid & 15;
    float g = 0.f;
    for (int ck = 0; ck < 8; ++ck) g += gramP[(long)(bh*8+ck)*256 + tid];
    g *= rq[bh*16+c] * rk[bh*16+d] * temps[bh & 7];
    float m = g;
    for (int off = 8; off >= 1; off >>= 1) m = fmaxf(m, __shfl_xor(m, off));
    float e = expf(g - m);
    float s = e;
    for (int off = 8; off >= 1; off >>= 1) s += __shfl_xor(s, off);
    attn[(long)bh*256 + tid] = e / s;
}

__global__ void k_outs(const float* __restrict__ attn, const float* __restrict__ V,
                       float* __restrict__ out) {
    int bh = blockIdx.x >> 6, nb = blockIdx.x & 63;
    int tid = threadIdx.x;
    __shared__ float aS[256];
    aS[tid] = attn[(long)bh*256 + tid];
    __syncthreads();
    long n = (long)nb*256 + tid;
    long rowb = (long)bh*16;
    float vv[16];
    #pragma unroll
    for (int dd = 0; dd < 16; ++dd) vv[dd] = V[(rowb+dd)*P + n];
    for (int cc = 0; cc < 16; ++cc) {
        float a = 0.f;
        #pragma unroll
        for (int dd = 0; dd < 16; ++dd) a = fmaf(aS[cc*16+dd], vv[dd], a);
        out[(rowb+cc)*P + n] = a;
    }
}

// ---------------------------------------------------------------------------
// Projection with 2 stacked inputs: out = W[:, :128]*A + W[:, 128:]*Bc (+out)
template<bool ADD>
__global__ void k_proj2in(const float* __restrict__ A, const float* __restrict__ Bc,
                          const float* __restrict__ W, float* __restrict__ out) {
    int pc = blockIdx.x, og = blockIdx.y, b = blockIdx.z;   // 64, 8, NB
    long p = (long)pc*256 + threadIdx.x;
    float acc[16];
    #pragma unroll
    for (int j = 0; j < 16; ++j) acc[j] = 0.f;
    long xb = (long)b*C*P + p;
    for (int c = 0; c < 128; ++c) {
        float v0 = A [xb + (long)c*P];
        float v1 = Bc[xb + (long)c*P];
        #pragma unroll
        for (int j = 0; j < 16; ++j) {
            int o = og*16 + j;
            acc[j] = fmaf(W[o*256 + c], v0, fmaf(W[o*256 + 128 + c], v1, acc[j]));
        }
    }
    long ob = (long)b*C*P + (long)(og*16)*P + p;
    #pragma unroll
    for (int j = 0; j < 16; ++j) {
        if (ADD) out[ob + (long)j*P] += acc[j];
        else     out[ob + (long)j*P]  = acc[j];
    }
}

// ---------------------------------------------------------------------------
static long ws_need_bytes(int bc) {
    long pb = (long)bc * C * P;          // one big buffer (floats)
    long extras = (long)bc*8*P           // Mg
                + (long)bc*128*3         // normF, recQ, recK
                + (long)bc*8*8*256*2     // gramC
                + (long)bc*8*256*2       // attn2
                + (long)bc*8*8*256       // gramS
                + (long)bc*8*256;        // attnS
    return (5*pb + extras) * 4;
}

extern "C" void kernel_launch(void* const* d_in, const int* in_sizes, int n_in,
                              void* d_out, int out_size, void* d_ws, size_t ws_size,
                              hipStream_t stream) {
    const float* x      = (const float*)d_in[0];
    const float* temp_f = (const float*)d_in[1];
    const float* w1     = (const float*)d_in[2];
    const float* b1     = (const float*)d_in[3];
    const float* bng    = (const float*)d_in[4];
    const float* bnb    = (const float*)d_in[5];
    const float* bnm    = (const float*)d_in[6];
    const float* bnv    = (const float*)d_in[7];
    const float* w2     = (const float*)d_in[8];
    const float* b2     = (const float*)d_in[9];
    const float* projf  = (const float*)d_in[10];
    const float* temp_s = (const float*)d_in[11];
    const float* q1w = (const float*)d_in[12]; const float* q1b = (const float*)d_in[13];
    const float* k1w = (const float*)d_in[14]; const float* k1b = (const float*)d_in[15];
    const float* v1w = (const float*)d_in[16]; const float* v1b = (const float*)d_in[17];
    const float* q3w = (const float*)d_in[18]; const float* q5w = (const float*)d_in[19];
    const float* k3w = (const float*)d_in[20]; const float* k5w = (const float*)d_in[21];
    const float* v3w = (const float*)d_in[22]; const float* v5w = (const float*)d_in[23];
    const float* c3w = (const float*)d_in[24]; const float* c5w = (const float*)d_in[25];
    const float* projs  = (const float*)d_in[26];
    float* out = (float*)d_out;
    float* ws = (float*)d_ws;

    // Pick the largest batch-chunk that fits the workspace (5 big buffers now)
    int bc = 1;
    if ((long)ws_size >= ws_need_bytes(8)) bc = 8;
    else if ((long)ws_size >= ws_need_bytes(4)) bc = 4;
    else if ((long)ws_size >= ws_need_bytes(2)) bc = 2;
    const int NB = bc;
    const long pb = (long)bc * C * P;

    float* t0 = ws + 0*pb;
    float* t1 = ws + 1*pb;
    float* t2 = ws + 2*pb;
    float* t3 = ws + 3*pb;
    float* t4 = ws + 4*pb;
    float* Mg    = ws + 5*pb;                       // bc*8*P
    float* normF = Mg + (long)bc*8*P;               // bc*128
    float* recQ  = normF + (long)bc*128;
    float* recK  = recQ + (long)bc*128;
    float* gramC = recK + (long)bc*128;             // bc*8*8*256*2
    float* attn2 = gramC + (long)bc*8*8*256*2;      // bc*8*256*2
    float* gramS = attn2 + (long)bc*8*256*2;        // bc*8*8*256
    float* attnS = gramS + (long)bc*8*8*256;        // bc*8*256

    for (int ckk = 0; ckk < 8/bc; ++ckk) {
        const float* xc = x + (long)ckk * bc * C * P;
        float* outc = out + (long)ckk * bc * C * P;

        // ================= frequency branch =================
        k_dft_rows_fwd<<<NB*C*HH, 128, 0, stream>>>(xc, t0, t1);
        k_dft_cols_x1<-1><<<NB*C*2, 512, 0, stream>>>(t0, t1, t2, t3);   // XF=(t2,t3)
        k_gate_mid<<<(NB*P)/256, 256, 0, stream>>>(t2, w1, b1, bng, bnb, bnm, bnv, Mg);
        k_gate_idft_x1<<<NB*C*2, 512, 0, stream>>>(t2, t3, Mg, w2, b2, t0, t1);
        k_idft_rows_abs<<<NB*C*HH, 128, 0, stream>>>(t0, t1, t4);        // OFL=t4
        k_norms_c<<<NB*C, 256, 0, stream>>>(t2, t3, normF);
        k_gram_c<<<NB*8*8, 256, 0, stream>>>(t2, t3, gramC);
        k_attn_f<<<NB*8, 256, 0, stream>>>(gramC, normF, temp_f, attn2);
        k_yf<<<NB*8*64, 256, 0, stream>>>(attn2, t2, t3, t0, t1);        // Y=(t0,t1)
        k_dft_cols_x1<+1><<<NB*C*2, 512, 0, stream>>>(t0, t1, t2, t3);   // B1=(t2,t3)
        k_pass2x<<<NB*C*8, 128, 0, stream>>>(t2, t3, t0);                // OF=t0
        k_proj2in<false><<<dim3(64, 8, NB), 256, 0, stream>>>(t0, t4, projf, outc);

        // ================= spatial branch =================
        k_conv1x1qkv<<<dim3(64, 24, NB), 256, 0, stream>>>(xc, q1w, q1b, k1w, k1b,
                                                           v1w, v1b, t0, t1, t2);
        k_gconv<<<NB*128*64, 256, 0, stream>>>(t0, q3w, q5w, t3);   // QS=t3
        k_gconv<<<NB*128*64, 256, 0, stream>>>(t1, k3w, k5w, t4);   // KS=t4
        k_gconv<<<NB*128*64, 256, 0, stream>>>(t2, v3w, v5w, t0);   // VS=t0
        k_gconv<<<NB*128*64, 256, 0, stream>>>(xc, c3w, c5w, t1);   // OSL=t1
        k_norms_r<<<NB*C, 256, 0, stream>>>(t3, recQ);
        k_norms_r<<<NB*C, 256, 0, stream>>>(t4, recK);
        k_gram_r<<<NB*8*8, 256, 0, stream>>>(t3, t4, gramS);
        k_attn_s<<<NB*8, 256, 0, stream>>>(gramS, recQ, recK, temp_s, attnS);
        k_outs<<<NB*8*64, 256, 0, stream>>>(attnS, t0, t2);         // OS=t2
        k_proj2in<true><<<dim3(64, 8, NB), 256, 0, stream>>>(t2, t1, projs, outc);
    }
}

// Round 4
// 4426.861 us; speedup vs baseline: 1.5655x; 1.1731x over previous
//
#include <hip/hip_runtime.h>
#include <math.h>

#define B 8
#define C 128
#define HEADS 8
#define HD 16
#define HH 128
#define WW 128
#define P 16384          // HH*WW

static __device__ __forceinline__ float PI2F() { return 6.28318530717958647692f; }

// ---------------------------------------------------------------------------
// Forward DFT-128 along contiguous (w) axis; REAL input. Hermitian: only
// k=0..64 computed/stored (downstream reads only cols 0..64).
// Block = 2 rows x 64 threads (k=0..63); k=64 (= alternating-sign sum, real)
// accumulated by all lanes, lane 0 stores it.
__global__ __launch_bounds__(128) void k_rrow_half(const float* __restrict__ x,
                                                   float* __restrict__ outR,
                                                   float* __restrict__ outI) {
    int row = blockIdx.x*2 + (threadIdx.x >> 6);
    int k = threadIdx.x & 63;
    long base = (long)row * 128;
    float a = -PI2F() * (float)k / 128.0f;
    float cs = __cosf(a), sn = __sinf(a);
    float twr = 1.f, twi = 0.f, ar = 0.f, ai = 0.f, a64 = 0.f, sgn = 1.f;
    for (int w = 0; w < 128; ++w) {
        float xv = x[base + w];      // lane-uniform -> scalar load
        ar = fmaf(xv, twr, ar);
        ai = fmaf(xv, twi, ai);
        a64 = fmaf(xv, sgn, a64);
        sgn = -sgn;
        float nr = fmaf(twr, cs, -twi * sn);
        twi = fmaf(twr, sn, twi * cs);
        twr = nr;
    }
    outR[base + k] = ar;
    outI[base + k] = ai;
    if (k == 0) { outR[base + 64] = a64; outI[base + 64] = 0.f; }
}

// ---------------------------------------------------------------------------
// Forward DFT-128 over the strided (h) axis producing XF, Hermitian-complete:
// computes columns k2=0..63 only; writes primary + conjugate reflection
// (fills cols 65..127). Col 64 handled by k_fcol64.
// Block = 1 image, 512 threads: kg=tid>>6 (k1=kg*16+j), lane=tid&63 (k2).
__global__ __launch_bounds__(512) void k_fcols_herm(
        const float* __restrict__ inR, const float* __restrict__ inI,
        float* __restrict__ outR, float* __restrict__ outI) {
    __shared__ float2 tw[128];
    __shared__ float sR[16][64], sI[16][64];
    int img = blockIdx.x;
    int tid = threadIdx.x;
    int lane = tid & 63, kg = tid >> 6;
    int kbase = kg*16;
    if (tid < 128) {
        float a = PI2F() * (float)tid / 128.0f;
        tw[tid] = make_float2(__cosf(a), -__sinf(a));   // sign -
    }
    long base = (long)img * P;
    float accR[16], accI[16];
    #pragma unroll
    for (int j = 0; j < 16; ++j) { accR[j] = 0.f; accI[j] = 0.f; }
    for (int h0 = 0; h0 < 128; h0 += 16) {
        __syncthreads();
        #pragma unroll
        for (int t = 0; t < 2; ++t) {
            int idx = tid + t*512;            // 0..1023 -> 16 rows x 64 cols
            int hh = idx >> 6, ln = idx & 63;
            sR[hh][ln] = inR[base + (h0+hh)*128 + ln];
            sI[hh][ln] = inI[base + (h0+hh)*128 + ln];
        }
        __syncthreads();
        for (int hh = 0; hh < 16; ++hh) {
            float xr = sR[hh][lane], xi = sI[hh][lane];
            int h = h0 + hh;
            #pragma unroll
            for (int j = 0; j < 16; ++j) {
                int k1 = kbase + j;
                float2 t = tw[(h*k1) & 127];   // wave-uniform broadcast
                accR[j] = fmaf(xr, t.x, fmaf(-xi, t.y, accR[j]));
                accI[j] = fmaf(xr, t.y, fmaf( xi, t.x, accI[j]));
            }
        }
    }
    #pragma unroll
    for (int j = 0; j < 16; ++j) {
        int k1 = kbase + j;
        outR[base + k1*128 + lane] = accR[j];
        outI[base + k1*128 + lane] = accI[j];
        if (lane > 0) {
            int k1r = (128 - k1) & 127;
            long ro = base + k1r*128 + (128 - lane);
            outR[ro] =  accR[j];
            outI[ro] = -accI[j];
        }
    }
}

// ---------------------------------------------------------------------------
// Column k2=64 of the forward col-DFT (input col 64 is real).
__global__ __launch_bounds__(128) void k_fcol64(const float* __restrict__ inR,
                                                float* __restrict__ outR,
                                                float* __restrict__ outI) {
    __shared__ float av[128];
    __shared__ float2 tw[128];
    int img = blockIdx.x;
    int tid = threadIdx.x;
    long base = (long)img * P;
    av[tid] = inR[base + tid*128 + 64];
    {
        float a = PI2F() * (float)tid / 128.0f;
        tw[tid] = make_float2(__cosf(a), -__sinf(a));
    }
    __syncthreads();
    float ar = 0.f, ai = 0.f;
    for (int h = 0; h < 128; ++h) {
        float xv = av[h];
        float2 t = tw[(h*tid) & 127];
        ar = fmaf(xv, t.x, ar);
        ai = fmaf(xv, t.y, ai);
    }
    outR[base + tid*128 + 64] = ar;
    outI[base + tid*128 + 64] = ai;
}

// ---------------------------------------------------------------------------
// SE gate stage 1: M[b,j,p] = relu(bn(b1[j] + sum_c W1[j][c]*XFr[b,c,p]))
__global__ void k_gate_mid(const float* __restrict__ XFr, const float* __restrict__ w1,
                           const float* __restrict__ b1, const float* __restrict__ gamma,
                           const float* __restrict__ beta, const float* __restrict__ mean,
                           const float* __restrict__ var, float* __restrict__ M) {
    __shared__ float w1s[8*128];
    int tid = threadIdx.x;
    for (int i = tid; i < 1024; i += 256) w1s[i] = w1[i];
    __syncthreads();
    long idx = (long)blockIdx.x * 256 + tid;
    int b = (int)(idx >> 14);
    int p = (int)(idx & 16383);
    float acc[8];
    #pragma unroll
    for (int j = 0; j < 8; ++j) acc[j] = b1[j];
    const float* xb = XFr + (long)b * C * P + p;
    for (int c = 0; c < 128; ++c) {
        float xv = xb[(long)c * P];
        #pragma unroll
        for (int j = 0; j < 8; ++j) acc[j] = fmaf(w1s[j*128 + c], xv, acc[j]);
    }
    #pragma unroll
    for (int j = 0; j < 8; ++j) {
        float v = (acc[j] - mean[j]) * rsqrtf(var[j] + 1e-5f) * gamma[j] + beta[j];
        M[((long)b*8 + j)*P + p] = fmaxf(v, 0.f);
    }
}

// ---------------------------------------------------------------------------
// Gate stage 2 fused with IDFT-128 over h; only columns k2=0..63 (Hermitian:
// downstream real-IDFT needs 0..64; col 64 via k_gcol64).
__global__ __launch_bounds__(512) void k_gate_idft65(
        const float* __restrict__ XFr, const float* __restrict__ XFi,
        const float* __restrict__ Mg, const float* __restrict__ w2,
        const float* __restrict__ b2,
        float* __restrict__ outR, float* __restrict__ outI) {
    __shared__ float2 tw[128];
    __shared__ float sR[16][64], sI[16][64];
    int img = blockIdx.x;
    int tid = threadIdx.x;
    int lane = tid & 63, kg = tid >> 6;
    int kbase = kg*16;
    if (tid < 128) {
        float a = PI2F() * (float)tid / 128.0f;
        tw[tid] = make_float2(__cosf(a), __sinf(a));    // sign +
    }
    int b = img >> 7, c = img & 127;
    float w2r[8];
    #pragma unroll
    for (int j = 0; j < 8; ++j) w2r[j] = w2[c*8 + j];
    float b2c = b2[c];
    long base = (long)img * P;
    const float* mb = Mg + (long)b*8*P;
    float accR[16], accI[16];
    #pragma unroll
    for (int j = 0; j < 16; ++j) { accR[j] = 0.f; accI[j] = 0.f; }
    for (int h0 = 0; h0 < 128; h0 += 16) {
        __syncthreads();
        #pragma unroll
        for (int t = 0; t < 2; ++t) {
            int idx = tid + t*512;
            int hh = idx >> 6, ln = idx & 63;
            int off = (h0+hh)*128 + ln;
            float z = b2c;
            #pragma unroll
            for (int j = 0; j < 8; ++j) z = fmaf(w2r[j], mb[(long)j*P + off], z);
            float g = 1.0f / (1.0f + __expf(-z));
            sR[hh][ln] = g * XFr[base + off];
            sI[hh][ln] = g * XFi[base + off];
        }
        __syncthreads();
        for (int hh = 0; hh < 16; ++hh) {
            float xr = sR[hh][lane], xi = sI[hh][lane];
            int h = h0 + hh;
            #pragma unroll
            for (int j = 0; j < 16; ++j) {
                int k1 = kbase + j;
                float2 t = tw[(h*k1) & 127];
                accR[j] = fmaf(xr, t.x, fmaf(-xi, t.y, accR[j]));
                accI[j] = fmaf(xr, t.y, fmaf( xi, t.x, accI[j]));
            }
        }
    }
    #pragma unroll
    for (int j = 0; j < 16; ++j) {
        int k1 = kbase + j;
        outR[base + k1*128 + lane] = accR[j];
        outI[base + k1*128 + lane] = accI[j];
    }
}

// ---------------------------------------------------------------------------
// Column 64 of the gate h-IDFT: g*XF col 64 then IDFT over h.
__global__ __launch_bounds__(128) void k_gcol64(
        const float* __restrict__ XFr, const float* __restrict__ XFi,
        const float* __restrict__ Mg, const float* __restrict__ w2,
        const float* __restrict__ b2,
        float* __restrict__ outR, float* __restrict__ outI) {
    __shared__ float gr[128], gi[128];
    __shared__ float2 tw[128];
    int img = blockIdx.x;
    int tid = threadIdx.x;
    int b = img >> 7, c = img & 127;
    long base = (long)img * P;
    const float* mb = Mg + (long)b*8*P;
    {
        int off = tid*128 + 64;
        float z = b2[c];
        #pragma unroll
        for (int j = 0; j < 8; ++j) z = fmaf(w2[c*8 + j], mb[(long)j*P + off], z);
        float g = 1.0f / (1.0f + __expf(-z));
        gr[tid] = g * XFr[base + off];
        gi[tid] = g * XFi[base + off];
        float a = PI2F() * (float)tid / 128.0f;
        tw[tid] = make_float2(__cosf(a), __sinf(a));
    }
    __syncthreads();
    float ar = 0.f, ai = 0.f;
    for (int h = 0; h < 128; ++h) {
        float xr = gr[h], xi = gi[h];
        float2 t = tw[(h*tid) & 127];
        ar = fmaf(xr, t.x, fmaf(-xi, t.y, ar));
        ai = fmaf(xr, t.y, fmaf( xi, t.x, ai));
    }
    outR[base + tid*128 + 64] = ar;
    outI[base + tid*128 + 64] = ai;
}

// ---------------------------------------------------------------------------
// Real-output IDFT-128 over contiguous axis from Hermitian half-spectrum
// (reads cols 0..64 only) + 1/16384 scale + abs. Block = 2 rows x 128 thr.
__global__ __launch_bounds__(256) void k_irow_herm(const float* __restrict__ Zr,
                                                   const float* __restrict__ Zi,
                                                   float* __restrict__ out) {
    int row = blockIdx.x*2 + (threadIdx.x >> 7);
    int p = threadIdx.x & 127;
    long base = (long)row * 128;
    float z0 = Zr[base];
    float z64 = Zr[base + 64];
    float a = PI2F() * (float)p / 128.0f;
    float cs = __cosf(a), sn = __sinf(a);
    float wr = cs, wi = sn;       // omega^{p*1}
    float acc = 0.f;
    for (int k = 1; k < 64; ++k) {
        float zr = Zr[base + k], zi = Zi[base + k];   // lane-uniform
        acc = fmaf(zr, wr, fmaf(-zi, wi, acc));
        float nr = fmaf(wr, cs, -wi * sn);
        wi = fmaf(wr, sn, wi * cs);
        wr = nr;
    }
    float v = z0 + ((p & 1) ? -z64 : z64) + 2.0f * acc;
    out[base + p] = fabsf(v) * (1.0f/16384.0f);
}

// ---------------------------------------------------------------------------
// Full complex DFT-128 over strided axis (kept for the non-Hermitian Y chain)
template<int SIGN>
__global__ __launch_bounds__(512) void k_dft_cols_x1(
        const float* __restrict__ inR, const float* __restrict__ inI,
        float* __restrict__ outR, float* __restrict__ outI) {
    __shared__ float2 tw[128];
    __shared__ float sR[16][128], sI[16][128];
    int img = blockIdx.x >> 1;
    int half = blockIdx.x & 1;
    int tid = threadIdx.x;
    int lane = tid & 127, kg = tid >> 7;
    int kbase = half*64 + kg*16;
    if (tid < 128) {
        float a = PI2F() * (float)tid / 128.0f;
        tw[tid] = make_float2(__cosf(a), SIGN > 0 ? __sinf(a) : -__sinf(a));
    }
    long base = (long)img * P;
    float accR[16], accI[16];
    #pragma unroll
    for (int j = 0; j < 16; ++j) { accR[j] = 0.f; accI[j] = 0.f; }
    for (int h0 = 0; h0 < 128; h0 += 16) {
        __syncthreads();
        #pragma unroll
        for (int t = 0; t < 4; ++t) {
            int idx = tid + t*512;
            int hh = idx >> 7, ln = idx & 127;
            sR[hh][ln] = inR[base + (h0+hh)*128 + ln];
            sI[hh][ln] = inI[base + (h0+hh)*128 + ln];
        }
        __syncthreads();
        for (int hh = 0; hh < 16; ++hh) {
            float xr = sR[hh][lane], xi = sI[hh][lane];
            int h = h0 + hh;
            #pragma unroll
            for (int j = 0; j < 16; ++j) {
                int k = kbase + j;
                float2 t = tw[(h*k) & 127];
                accR[j] = fmaf(xr, t.x, fmaf(-xi, t.y, accR[j]));
                accI[j] = fmaf(xr, t.y, fmaf( xi, t.x, accI[j]));
            }
        }
    }
    #pragma unroll
    for (int j = 0; j < 16; ++j) {
        int k = kbase + j;
        outR[base + k*128 + lane] = accR[j];
        outI[base + k*128 + lane] = accI[j];
    }
}

// ---------------------------------------------------------------------------
// Row-wise L2 norm reciprocals (complex / real)
__global__ void k_norms_c(const float* __restrict__ Xr, const float* __restrict__ Xi,
                          float* __restrict__ recip) {
    int row = blockIdx.x; int tid = threadIdx.x;
    long base = (long)row * P;
    float s = 0.f;
    for (int n = tid; n < P; n += 256) {
        float r = Xr[base+n], i = Xi[base+n];
        s = fmaf(r, r, fmaf(i, i, s));
    }
    __shared__ float red[256];
    red[tid] = s; __syncthreads();
    for (int st = 128; st > 0; st >>= 1) {
        if (tid < st) red[tid] += red[tid+st];
        __syncthreads();
    }
    if (tid == 0) recip[row] = 1.0f / fmaxf(sqrtf(red[0]), 1e-12f);
}

__global__ void k_norms_r(const float* __restrict__ X, float* __restrict__ recip) {
    int row = blockIdx.x; int tid = threadIdx.x;
    long base = (long)row * P;
    float s = 0.f;
    for (int n = tid; n < P; n += 256) { float v = X[base+n]; s = fmaf(v, v, s); }
    __shared__ float red[256];
    red[tid] = s; __syncthreads();
    for (int st = 128; st > 0; st >>= 1) {
        if (tid < st) red[tid] += red[tid+st];
        __syncthreads();
    }
    if (tid == 0) recip[row] = 1.0f / fmaxf(sqrtf(red[0]), 1e-12f);
}

// ---------------------------------------------------------------------------
// Complex Gram, REAL part only (imag is exactly 0 by Hermitian symmetry):
// G[c][d] = sum_n (qr*rr - qi*ri)
__global__ void k_gram_cr(const float* __restrict__ Xr, const float* __restrict__ Xi,
                          float* __restrict__ gramP) {
    int bh = blockIdx.x >> 3, ck = blockIdx.x & 7;
    int tid = threadIdx.x; int c = tid >> 4, d = tid & 15;
    long bc = ((long)bh*16 + c) * P;
    long bd = ((long)bh*16 + d) * P;
    int n0 = ck * 2048;
    float ar = 0.f;
    for (int n = n0; n < n0 + 2048; ++n) {
        ar = fmaf(Xr[bc+n], Xr[bd+n], fmaf(-Xi[bc+n], Xi[bd+n], ar));
    }
    gramP[(long)(bh*8 + ck)*256 + tid] = ar;
}

// ---------------------------------------------------------------------------
// attn_f: real gram -> softmax; imag part is exactly uniform 1/16.
// Then IDFT-16 over c (1/16 folded) -> complex attn2.
__global__ void k_attn_f(const float* __restrict__ gramP, const float* __restrict__ recip,
                         const float* __restrict__ tempf, float* __restrict__ attn2) {
    int bh = blockIdx.x; int tid = threadIdx.x;
    int c = tid >> 4, d = tid & 15;
    int hh = bh & 7;
    float gr = 0.f;
    for (int ck = 0; ck < 8; ++ck) gr += gramP[(long)(bh*8+ck)*256 + tid];
    float vr = gr * recip[bh*16+c] * recip[bh*16+d] * tempf[hh];
    float mr = vr;
    for (int off = 8; off >= 1; off >>= 1) mr = fmaxf(mr, __shfl_xor(mr, off));
    float er = __expf(vr - mr);
    float ssr = er;
    for (int off = 8; off >= 1; off >>= 1) ssr += __shfl_xor(ssr, off);
    float arv = er / ssr;
    const float u = 1.0f/16.0f;      // imag softmax of all-zero row
    __shared__ float sR[256];
    __shared__ float2 t16[16];
    sR[tid] = arv;
    if (tid < 16) {
        float a = PI2F() * (float)tid / 16.0f;
        t16[tid] = make_float2(__cosf(a), __sinf(a));
    }
    __syncthreads();
    float ar2 = 0.f, ai2 = 0.f;
    #pragma unroll
    for (int cc = 0; cc < 16; ++cc) {
        float2 t = t16[(cc*c) & 15];
        float xr = sR[cc*16 + d];
        ar2 = fmaf(xr, t.x, fmaf(-u, t.y, ar2));
        ai2 = fmaf(xr, t.y, fmaf( u, t.x, ai2));
    }
    long o = ((long)bh*256 + tid)*2;
    attn2[o]   = ar2 * (1.0f/16.0f);
    attn2[o+1] = ai2 * (1.0f/16.0f);
}

// ---------------------------------------------------------------------------
// Y[c][n] = sum_d attn2[c][d] * qf[d][n]   (complex)
__global__ void k_yf(const float* __restrict__ attn2, const float* __restrict__ Xr,
                     const float* __restrict__ Xi, float* __restrict__ Yr,
                     float* __restrict__ Yi) {
    int bh = blockIdx.x >> 6;
    int nb = blockIdx.x & 63;
    int tid = threadIdx.x;
    __shared__ float aR[256], aI[256];
    { long o = ((long)bh*256 + tid)*2; aR[tid] = attn2[o]; aI[tid] = attn2[o+1]; }
    __syncthreads();
    long n = (long)nb*256 + tid;
    long rowb = (long)bh*16;
    float qr[16], qi[16];
    #pragma unroll
    for (int dd = 0; dd < 16; ++dd) {
        qr[dd] = Xr[(rowb+dd)*P + n];
        qi[dd] = Xi[(rowb+dd)*P + n];
    }
    for (int cc = 0; cc < 16; ++cc) {
        float ar = 0.f, ai = 0.f;
        #pragma unroll
        for (int dd = 0; dd < 16; ++dd) {
            float tr = aR[cc*16+dd], ti = aI[cc*16+dd];
            ar = fmaf(tr, qr[dd], fmaf(-ti, qi[dd], ar));
            ai = fmaf(tr, qi[dd], fmaf( ti, qr[dd], ai));
        }
        Yr[(rowb+cc)*P + n] = ar;
        Yi[(rowb+cc)*P + n] = ai;
    }
}

// ---------------------------------------------------------------------------
// Length-16384 IFFT pass 2 + abs (CT 128x128), LDS premultiply version.
__global__ __launch_bounds__(128) void k_pass2x(const float* __restrict__ B1r,
                                                const float* __restrict__ B1i,
                                                float* __restrict__ out) {
    __shared__ float Dr[16][128], Di[16][128];
    int img = blockIdx.x >> 3;
    int k2g = blockIdx.x & 7;
    int tid = threadIdx.x;           // 128 threads, tid = k1
    long base = (long)img * P;
    const float* pr = B1r + base + (long)k2g*2048;
    const float* pi = B1i + base + (long)k2g*2048;
    #pragma unroll
    for (int t = 0; t < 16; ++t) {
        int idx = tid + t*128;
        int j = idx >> 7, n1 = idx & 127;
        float br = pr[idx], bi = pi[idx];
        float ang = (PI2F()/16384.0f) * (float)(n1 * (k2g*16 + j));
        float s, cz;
        __sincosf(ang, &s, &cz);
        Dr[j][n1] = br*cz - bi*s;
        Di[j][n1] = br*s + bi*cz;
    }
    __syncthreads();
    float sr, si;
    __sincosf(PI2F() * (float)tid / 128.0f, &si, &sr);
    float wr = 1.f, wi = 0.f;
    float accR[16], accI[16];
    #pragma unroll
    for (int j = 0; j < 16; ++j) { accR[j] = 0.f; accI[j] = 0.f; }
    for (int n1 = 0; n1 < 128; ++n1) {
        #pragma unroll
        for (int j = 0; j < 16; ++j) {
            float dr = Dr[j][n1], di = Di[j][n1];
            accR[j] = fmaf(dr, wr, fmaf(-di, wi, accR[j]));
            accI[j] = fmaf(dr, wi, fmaf( di, wr, accI[j]));
        }
        float nr = fmaf(wr, sr, -wi*si);
        wi = fmaf(wr, si, wi*sr);
        wr = nr;
    }
    float4 v[4];
    #pragma unroll
    for (int j = 0; j < 16; ++j) {
        ((float*)v)[j] = sqrtf(accR[j]*accR[j] + accI[j]*accI[j]) * (1.0f/16384.0f);
    }
    float4* op = (float4*)(out + base + (long)tid*128 + k2g*16);
    #pragma unroll
    for (int q = 0; q < 4; ++q) op[q] = v[q];
}

// ---------------------------------------------------------------------------
// q/k/v 1x1 convs (one launch; which = q/k/v). 16 outch per thread.
__global__ void k_conv1x1qkv(const float* __restrict__ x,
                             const float* __restrict__ Wq, const float* __restrict__ bq,
                             const float* __restrict__ Wk, const float* __restrict__ bk,
                             const float* __restrict__ Wv, const float* __restrict__ bv,
                             float* __restrict__ Oq, float* __restrict__ Ok,
                             float* __restrict__ Ov) {
    int pc = blockIdx.x;
    int og = blockIdx.y & 7, which = blockIdx.y >> 3;
    int b = blockIdx.z;
    const float* W    = which == 0 ? Wq : which == 1 ? Wk : Wv;
    const float* bias = which == 0 ? bq : which == 1 ? bk : bv;
    float* O          = which == 0 ? Oq : which == 1 ? Ok : Ov;
    long p = (long)pc*256 + threadIdx.x;
    float acc[16];
    #pragma unroll
    for (int j = 0; j < 16; ++j) acc[j] = bias[og*16+j];
    const float* xb = x + (long)b*C*P + p;
    for (int c = 0; c < 128; ++c) {
        float xv = xb[(long)c*P];
        #pragma unroll
        for (int j = 0; j < 16; ++j)
            acc[j] = fmaf(W[(og*16+j)*128 + c], xv, acc[j]);
    }
    long ob = (long)b*C*P + (long)(og*16)*P + p;
    #pragma unroll
    for (int j = 0; j < 16; ++j) O[ob + (long)j*P] = acc[j];
}

// ---------------------------------------------------------------------------
// Grouped conv: out ch g<64 = 3x3(pad1) over in ch (2g,2g+1); g>=64 = 5x5(pad2)
__global__ void k_gconv(const float* __restrict__ in, const float* __restrict__ w3,
                        const float* __restrict__ w5, float* __restrict__ out) {
    int bid = blockIdx.x;
    int pc = bid & 63;
    int ch = (bid >> 6) & 127;
    int b  = bid >> 13;
    int p = pc*256 + threadIdx.x;
    int h = p >> 7, w = p & 127;
    float acc = 0.f;
    if (ch < 64) {
        int g = ch;
        const float* ib = in + ((long)b*C + 2*g)*P;
        #pragma unroll
        for (int ic = 0; ic < 2; ++ic) {
            const float* wp = w3 + (g*2 + ic)*9;
            #pragma unroll
            for (int ky = 0; ky < 3; ++ky) {
                int h2 = h + ky - 1;
                if (h2 < 0 || h2 > 127) continue;
                #pragma unroll
                for (int kx = 0; kx < 3; ++kx) {
                    int w2_ = w + kx - 1;
                    if (w2_ < 0 || w2_ > 127) continue;
                    acc = fmaf(wp[ky*3+kx], ib[(long)ic*P + h2*128 + w2_], acc);
                }
            }
        }
    } else {
        int g = ch - 64;
        const float* ib = in + ((long)b*C + 2*g)*P;
        #pragma unroll
        for (int ic = 0; ic < 2; ++ic) {
            const float* wp = w5 + (g*2 + ic)*25;
            #pragma unroll
            for (int ky = 0; ky < 5; ++ky) {
                int h2 = h + ky - 2;
                if (h2 < 0 || h2 > 127) continue;
                #pragma unroll
                for (int kx = 0; kx < 5; ++kx) {
                    int w2_ = w + kx - 2;
                    if (w2_ < 0 || w2_ > 127) continue;
                    acc = fmaf(wp[ky*5+kx], ib[(long)ic*P + h2*128 + w2_], acc);
                }
            }
        }
    }
    out[((long)b*C + ch)*P + p] = acc;
}

// ---------------------------------------------------------------------------
__global__ void k_gram_r(const float* __restrict__ Q, const float* __restrict__ K,
                         float* __restrict__ gramP) {
    int bh = blockIdx.x >> 3, ck = blockIdx.x & 7;
    int tid = threadIdx.x; int c = tid >> 4, d = tid & 15;
    long bc = ((long)bh*16 + c) * P;
    long bd = ((long)bh*16 + d) * P;
    int n0 = ck*2048;
    float a = 0.f;
    for (int n = n0; n < n0+2048; ++n)
        a = fmaf(Q[bc+n], K[bd+n], a);
    gramP[(long)(bh*8+ck)*256 + tid] = a;
}

__global__ void k_attn_s(const float* __restrict__ gramP, const float* __restrict__ rq,
                         const float* __restrict__ rk, const float* __restrict__ temps,
                         float* __restrict__ attn) {
    int bh = blockIdx.x; int tid = threadIdx.x;
    int c = tid >> 4, d = tid & 15;
    float g = 0.f;
    for (int ck = 0; ck < 8; ++ck) g += gramP[(long)(bh*8+ck)*256 + tid];
    g *= rq[bh*16+c] * rk[bh*16+d] * temps[bh & 7];
    float m = g;
    for (int off = 8; off >= 1; off >>= 1) m = fmaxf(m, __shfl_xor(m, off));
    float e = __expf(g - m);
    float s = e;
    for (int off = 8; off >= 1; off >>= 1) s += __shfl_xor(s, off);
    attn[(long)bh*256 + tid] = e / s;
}

__global__ void k_outs(const float* __restrict__ attn, const float* __restrict__ V,
                       float* __restrict__ out) {
    int bh = blockIdx.x >> 6, nb = blockIdx.x & 63;
    int tid = threadIdx.x;
    __shared__ float aS[256];
    aS[tid] = attn[(long)bh*256 + tid];
    __syncthreads();
    long n = (long)nb*256 + tid;
    long rowb = (long)bh*16;
    float vv[16];
    #pragma unroll
    for (int dd = 0; dd < 16; ++dd) vv[dd] = V[(rowb+dd)*P + n];
    for (int cc = 0; cc < 16; ++cc) {
        float a = 0.f;
        #pragma unroll
        for (int dd = 0; dd < 16; ++dd) a = fmaf(aS[cc*16+dd], vv[dd], a);
        out[(rowb+cc)*P + n] = a;
    }
}

// ---------------------------------------------------------------------------
// Projection with 2 stacked inputs: out = W[:, :128]*A + W[:, 128:]*Bc (+out)
template<bool ADD>
__global__ void k_proj2in(const float* __restrict__ A, const float* __restrict__ Bc,
                          const float* __restrict__ W, float* __restrict__ out) {
    int pc = blockIdx.x, og = blockIdx.y, b = blockIdx.z;
    long p = (long)pc*256 + threadIdx.x;
    float acc[16];
    #pragma unroll
    for (int j = 0; j < 16; ++j) acc[j] = 0.f;
    long xb = (long)b*C*P + p;
    for (int c = 0; c < 128; ++c) {
        float v0 = A [xb + (long)c*P];
        float v1 = Bc[xb + (long)c*P];
        #pragma unroll
        for (int j = 0; j < 16; ++j) {
            int o = og*16 + j;
            acc[j] = fmaf(W[o*256 + c], v0, fmaf(W[o*256 + 128 + c], v1, acc[j]));
        }
    }
    long ob = (long)b*C*P + (long)(og*16)*P + p;
    #pragma unroll
    for (int j = 0; j < 16; ++j) {
        if (ADD) out[ob + (long)j*P] += acc[j];
        else     out[ob + (long)j*P]  = acc[j];
    }
}

// ---------------------------------------------------------------------------
static long ws_need_bytes(int bc) {
    long pb = (long)bc * C * P;
    long extras = (long)bc*8*P           // Mg
                + (long)bc*128*3         // normF, recQ, recK
                + (long)bc*8*8*256       // gramC (real now)
                + (long)bc*8*256*2       // attn2
                + (long)bc*8*8*256       // gramS
                + (long)bc*8*256;        // attnS
    return (5*pb + extras) * 4;
}

extern "C" void kernel_launch(void* const* d_in, const int* in_sizes, int n_in,
                              void* d_out, int out_size, void* d_ws, size_t ws_size,
                              hipStream_t stream) {
    const float* x      = (const float*)d_in[0];
    const float* temp_f = (const float*)d_in[1];
    const float* w1     = (const float*)d_in[2];
    const float* b1     = (const float*)d_in[3];
    const float* bng    = (const float*)d_in[4];
    const float* bnb    = (const float*)d_in[5];
    const float* bnm    = (const float*)d_in[6];
    const float* bnv    = (const float*)d_in[7];
    const float* w2     = (const float*)d_in[8];
    const float* b2     = (const float*)d_in[9];
    const float* projf  = (const float*)d_in[10];
    const float* temp_s = (const float*)d_in[11];
    const float* q1w = (const float*)d_in[12]; const float* q1b = (const float*)d_in[13];
    const float* k1w = (const float*)d_in[14]; const float* k1b = (const float*)d_in[15];
    const float* v1w = (const float*)d_in[16]; const float* v1b = (const float*)d_in[17];
    const float* q3w = (const float*)d_in[18]; const float* q5w = (const float*)d_in[19];
    const float* k3w = (const float*)d_in[20]; const float* k5w = (const float*)d_in[21];
    const float* v3w = (const float*)d_in[22]; const float* v5w = (const float*)d_in[23];
    const float* c3w = (const float*)d_in[24]; const float* c5w = (const float*)d_in[25];
    const float* projs  = (const float*)d_in[26];
    float* out = (float*)d_out;
    float* ws = (float*)d_ws;

    int bc = 1;
    if ((long)ws_size >= ws_need_bytes(8)) bc = 8;
    else if ((long)ws_size >= ws_need_bytes(4)) bc = 4;
    else if ((long)ws_size >= ws_need_bytes(2)) bc = 2;
    const int NB = bc;
    const long pb = (long)bc * C * P;

    float* t0 = ws + 0*pb;
    float* t1 = ws + 1*pb;
    float* t2 = ws + 2*pb;
    float* t3 = ws + 3*pb;
    float* t4 = ws + 4*pb;
    float* Mg    = ws + 5*pb;
    float* normF = Mg + (long)bc*8*P;
    float* recQ  = normF + (long)bc*128;
    float* recK  = recQ + (long)bc*128;
    float* gramC = recK + (long)bc*128;             // bc*8*8*256 (real)
    float* attn2 = gramC + (long)bc*8*8*256;        // bc*8*256*2
    float* gramS = attn2 + (long)bc*8*256*2;        // bc*8*8*256
    float* attnS = gramS + (long)bc*8*8*256;        // bc*8*256

    for (int ckk = 0; ckk < 8/bc; ++ckk) {
        const float* xc = x + (long)ckk * bc * C * P;
        float* outc = out + (long)ckk * bc * C * P;

        // ================= frequency branch =================
        k_rrow_half<<<NB*C*HH/2, 128, 0, stream>>>(xc, t0, t1);          // R cols 0..64
        k_fcols_herm<<<NB*C, 512, 0, stream>>>(t0, t1, t2, t3);          // XF (cols 0..63 + refl)
        k_fcol64<<<NB*C, 128, 0, stream>>>(t0, t2, t3);                  // XF col 64
        k_gate_mid<<<(NB*P)/256, 256, 0, stream>>>(t2, w1, b1, bng, bnb, bnm, bnv, Mg);
        k_gate_idft65<<<NB*C, 512, 0, stream>>>(t2, t3, Mg, w2, b2, t0, t1); // Z cols 0..63
        k_gcol64<<<NB*C, 128, 0, stream>>>(t2, t3, Mg, w2, b2, t0, t1);  // Z col 64
        k_irow_herm<<<NB*C*HH/2, 256, 0, stream>>>(t0, t1, t4);          // OFL=t4 (real IDFT)
        k_norms_c<<<NB*C, 256, 0, stream>>>(t2, t3, normF);
        k_gram_cr<<<NB*8*8, 256, 0, stream>>>(t2, t3, gramC);
        k_attn_f<<<NB*8, 256, 0, stream>>>(gramC, normF, temp_f, attn2);
        k_yf<<<NB*8*64, 256, 0, stream>>>(attn2, t2, t3, t0, t1);        // Y=(t0,t1)
        k_dft_cols_x1<+1><<<NB*C*2, 512, 0, stream>>>(t0, t1, t2, t3);   // B1=(t2,t3)
        k_pass2x<<<NB*C*8, 128, 0, stream>>>(t2, t3, t0);                // OF=t0
        k_proj2in<false><<<dim3(64, 8, NB), 256, 0, stream>>>(t0, t4, projf, outc);

        // ================= spatial branch =================
        k_conv1x1qkv<<<dim3(64, 24, NB), 256, 0, stream>>>(xc, q1w, q1b, k1w, k1b,
                                                           v1w, v1b, t0, t1, t2);
        k_gconv<<<NB*128*64, 256, 0, stream>>>(t0, q3w, q5w, t3);   // QS=t3
        k_gconv<<<NB*128*64, 256, 0, stream>>>(t1, k3w, k5w, t4);   // KS=t4
        k_gconv<<<NB*128*64, 256, 0, stream>>>(t2, v3w, v5w, t0);   // VS=t0
        k_gconv<<<NB*128*64, 256, 0, stream>>>(xc, c3w, c5w, t1);   // OSL=t1
        k_norms_r<<<NB*C, 256, 0, stream>>>(t3, recQ);
        k_norms_r<<<NB*C, 256, 0, stream>>>(t4, recK);
        k_gram_r<<<NB*8*8, 256, 0, stream>>>(t3, t4, gramS);
        k_attn_s<<<NB*8, 256, 0, stream>>>(gramS, recQ, recK, temp_s, attnS);
        k_outs<<<NB*8*64, 256, 0, stream>>>(attnS, t0, t2);         // OS=t2
        k_proj2in<true><<<dim3(64, 8, NB), 256, 0, stream>>>(t2, t1, projs, outc);
    }
}

// Round 5
// 3157.839 us; speedup vs baseline: 2.1947x; 1.4019x over previous
//
#include <hip/hip_runtime.h>
#include <math.h>

#define B 8
#define C 128
#define HEADS 8
#define HD 16
#define HH 128
#define WW 128
#define P 16384          // HH*WW

static __device__ __forceinline__ float PI2F() { return 6.28318530717958647692f; }

// ===========================================================================
// Radix-2 DIT FFT-128 along the STRIDED (h) axis. 32 columns per block,
// 256 threads, 32 KB LDS. Bit-reversed load -> 7 in-place stages -> natural
// store. Lanes map to columns, so butterfly LDS accesses are conflict-free
// and twiddle reads are wave-uniform broadcasts.
// GATE variant: staging multiplies by sigmoid(W2*Mg + b2) (SE gate fusion).
template<int SIGN, bool GATE>
__global__ __launch_bounds__(256) void k_fftcol(
        const float* __restrict__ inR, const float* __restrict__ inI,
        const float* __restrict__ Mg, const float* __restrict__ w2,
        const float* __restrict__ b2,
        float* __restrict__ outR, float* __restrict__ outI) {
    __shared__ float2 S[128*32];
    __shared__ float2 tw[64];
    int bid = blockIdx.x;
    int img = bid >> 2;
    int qo  = (bid & 3) * 32;
    int tid = threadIdx.x;
    if (tid < 64) {
        float a = PI2F() * (float)tid / 128.0f;
        float s_, c_; __sincosf(a, &s_, &c_);
        tw[tid] = make_float2(c_, SIGN > 0 ? s_ : -s_);
    }
    long base = (long)img * P;
    float w2r[8]; float b2c = 0.f;
    const float* mb = nullptr;
    if (GATE) {
        int c = img & 127;
        #pragma unroll
        for (int j = 0; j < 8; ++j) w2r[j] = w2[c*8 + j];
        b2c = b2[c];
        mb = Mg + (long)(img >> 7)*8*P;
    }
    #pragma unroll
    for (int t = 0; t < 16; ++t) {
        int idx = tid + t*256;
        int h = idx >> 5, cc = idx & 31;
        int off = h*128 + qo + cc;
        float xr = inR[base + off];
        float xi = inI[base + off];
        if (GATE) {
            float z = b2c;
            #pragma unroll
            for (int j = 0; j < 8; ++j) z = fmaf(w2r[j], mb[(long)j*P + off], z);
            float g = 1.0f / (1.0f + __expf(-z));
            xr *= g; xi *= g;
        }
        int hr = __brev(h) >> 25;          // 7-bit reversal
        S[hr*32 + cc] = make_float2(xr, xi);
    }
    __syncthreads();
    int ln = tid & 31, wid = tid >> 5;
    for (int s = 0; s < 7; ++s) {
        int half = 1 << s;
        #pragma unroll
        for (int q = 0; q < 8; ++q) {
            int j = wid*8 + q;               // 0..63, disjoint across threads
            int k = j & (half - 1);
            int g = j >> s;
            int i0 = (g << (s+1)) + k;
            int i1 = i0 + half;
            float2 u = S[i0*32 + ln];
            float2 v = S[i1*32 + ln];
            float2 w = tw[k << (6 - s)];     // wave-uniform broadcast
            float vr = v.x*w.x - v.y*w.y;
            float vi = v.x*w.y + v.y*w.x;
            S[i0*32 + ln] = make_float2(u.x + vr, u.y + vi);
            S[i1*32 + ln] = make_float2(u.x - vr, u.y - vi);
        }
        __syncthreads();
    }
    #pragma unroll
    for (int t = 0; t < 16; ++t) {
        int idx = tid + t*256;
        int k = idx >> 5, cc = idx & 31;
        float2 z = S[k*32 + cc];
        outR[base + k*128 + qo + cc] = z.x;
        outI[base + k*128 + qo + cc] = z.y;
    }
}

// ===========================================================================
// Radix-2 DIT FFT-128 along the CONTIGUOUS (w) axis. 4 rows/block, 256 thr.
// MODE 0: real input, sign -, write complex (forward rows of fft2)
// MODE 1: complex input, sign +, write |.|/16384 (final ifft2 row pass + abs)
// MODE 2: CT pass2: premultiply e^{+2pi i w*k2/16384}, sign +, |.|/16384,
//         transposed store out[k1*128 + k2] (float4 across 4 rows).
template<int MODE>
__global__ __launch_bounds__(256) void k_fftrow(
        const float* __restrict__ inR, const float* __restrict__ inI,
        float* __restrict__ out, float* __restrict__ outI) {
    __shared__ float2 S[4*128];
    __shared__ float2 tw[64];
    int bid = blockIdx.x;
    int img = bid >> 5;
    int r0  = (bid & 31) * 4;
    int tid = threadIdx.x;
    if (tid < 64) {
        float a = PI2F() * (float)tid / 128.0f;
        float s_, c_; __sincosf(a, &s_, &c_);
        tw[tid] = make_float2(c_, MODE == 0 ? -s_ : s_);
    }
    long base = (long)img * P;
    #pragma unroll
    for (int t = 0; t < 2; ++t) {
        int idx = tid + t*256;
        int r = idx >> 7, w = idx & 127;
        long off = base + (long)(r0 + r)*128 + w;
        float xr = inR[off];
        float xi = (MODE == 0) ? 0.f : inI[off];
        if (MODE == 2) {
            int k2 = r0 + r;
            float ang = (PI2F()/16384.0f) * (float)(w * k2);
            float s_, c_; __sincosf(ang, &s_, &c_);
            float yr = xr*c_ - xi*s_;
            float yi = xr*s_ + xi*c_;
            xr = yr; xi = yi;
        }
        S[r*128 + (__brev(w) >> 25)] = make_float2(xr, xi);
    }
    __syncthreads();
    int r = tid >> 6, j = tid & 63;          // 4 rows x 64 butterflies
    for (int s = 0; s < 7; ++s) {
        int half = 1 << s;
        int k = j & (half - 1);
        int g = j >> s;
        int i0 = (g << (s+1)) + k;
        int i1 = i0 + half;
        float2 u = S[r*128 + i0];
        float2 v = S[r*128 + i1];
        float2 w_ = tw[k << (6 - s)];
        float vr = v.x*w_.x - v.y*w_.y;
        float vi = v.x*w_.y + v.y*w_.x;
        S[r*128 + i0] = make_float2(u.x + vr, u.y + vi);
        S[r*128 + i1] = make_float2(u.x - vr, u.y - vi);
        __syncthreads();
    }
    if (MODE == 0) {
        #pragma unroll
        for (int t = 0; t < 2; ++t) {
            int idx = tid + t*256;
            int rr = idx >> 7, k = idx & 127;
            float2 z = S[rr*128 + k];
            long off = base + (long)(r0 + rr)*128 + k;
            out[off] = z.x; outI[off] = z.y;
        }
    } else if (MODE == 1) {
        #pragma unroll
        for (int t = 0; t < 2; ++t) {
            int idx = tid + t*256;
            int rr = idx >> 7, p = idx & 127;
            float2 z = S[rr*128 + p];
            out[base + (long)(r0 + rr)*128 + p] =
                sqrtf(z.x*z.x + z.y*z.y) * (1.0f/16384.0f);
        }
    } else {
        if (tid < 128) {
            int k1 = tid;
            float4 v;
            float2 z0 = S[0*128 + k1], z1 = S[1*128 + k1];
            float2 z2 = S[2*128 + k1], z3 = S[3*128 + k1];
            v.x = sqrtf(z0.x*z0.x + z0.y*z0.y) * (1.0f/16384.0f);
            v.y = sqrtf(z1.x*z1.x + z1.y*z1.y) * (1.0f/16384.0f);
            v.z = sqrtf(z2.x*z2.x + z2.y*z2.y) * (1.0f/16384.0f);
            v.w = sqrtf(z3.x*z3.x + z3.y*z3.y) * (1.0f/16384.0f);
            *(float4*)(out + base + (long)k1*128 + r0) = v;
        }
    }
}

// ---------------------------------------------------------------------------
// SE gate stage 1: M[b,j,p] = relu(bn(b1[j] + sum_c W1[j][c]*XFr[b,c,p]))
__global__ void k_gate_mid(const float* __restrict__ XFr, const float* __restrict__ w1,
                           const float* __restrict__ b1, const float* __restrict__ gamma,
                           const float* __restrict__ beta, const float* __restrict__ mean,
                           const float* __restrict__ var, float* __restrict__ M) {
    __shared__ float w1s[8*128];
    int tid = threadIdx.x;
    for (int i = tid; i < 1024; i += 256) w1s[i] = w1[i];
    __syncthreads();
    long idx = (long)blockIdx.x * 256 + tid;
    int b = (int)(idx >> 14);
    int p = (int)(idx & 16383);
    float acc[8];
    #pragma unroll
    for (int j = 0; j < 8; ++j) acc[j] = b1[j];
    const float* xb = XFr + (long)b * C * P + p;
    for (int c = 0; c < 128; ++c) {
        float xv = xb[(long)c * P];
        #pragma unroll
        for (int j = 0; j < 8; ++j) acc[j] = fmaf(w1s[j*128 + c], xv, acc[j]);
    }
    #pragma unroll
    for (int j = 0; j < 8; ++j) {
        float v = (acc[j] - mean[j]) * rsqrtf(var[j] + 1e-5f) * gamma[j] + beta[j];
        M[((long)b*8 + j)*P + p] = fmaxf(v, 0.f);
    }
}

// ---------------------------------------------------------------------------
// Row-wise L2 norm reciprocals (complex / real)
__global__ void k_norms_c(const float* __restrict__ Xr, const float* __restrict__ Xi,
                          float* __restrict__ recip) {
    int row = blockIdx.x; int tid = threadIdx.x;
    long base = (long)row * P;
    float s = 0.f;
    for (int n = tid; n < P; n += 256) {
        float r = Xr[base+n], i = Xi[base+n];
        s = fmaf(r, r, fmaf(i, i, s));
    }
    __shared__ float red[256];
    red[tid] = s; __syncthreads();
    for (int st = 128; st > 0; st >>= 1) {
        if (tid < st) red[tid] += red[tid+st];
        __syncthreads();
    }
    if (tid == 0) recip[row] = 1.0f / fmaxf(sqrtf(red[0]), 1e-12f);
}

__global__ void k_norms_r(const float* __restrict__ X, float* __restrict__ recip) {
    int row = blockIdx.x; int tid = threadIdx.x;
    long base = (long)row * P;
    float s = 0.f;
    for (int n = tid; n < P; n += 256) { float v = X[base+n]; s = fmaf(v, v, s); }
    __shared__ float red[256];
    red[tid] = s; __syncthreads();
    for (int st = 128; st > 0; st >>= 1) {
        if (tid < st) red[tid] += red[tid+st];
        __syncthreads();
    }
    if (tid == 0) recip[row] = 1.0f / fmaxf(sqrtf(red[0]), 1e-12f);
}

// ---------------------------------------------------------------------------
// Complex Gram, REAL part only (imag is exactly 0 by Hermitian symmetry)
__global__ void k_gram_cr(const float* __restrict__ Xr, const float* __restrict__ Xi,
                          float* __restrict__ gramP) {
    int bh = blockIdx.x >> 3, ck = blockIdx.x & 7;
    int tid = threadIdx.x; int c = tid >> 4, d = tid & 15;
    long bc = ((long)bh*16 + c) * P;
    long bd = ((long)bh*16 + d) * P;
    int n0 = ck * 2048;
    float ar = 0.f;
    for (int n = n0; n < n0 + 2048; ++n) {
        ar = fmaf(Xr[bc+n], Xr[bd+n], fmaf(-Xi[bc+n], Xi[bd+n], ar));
    }
    gramP[(long)(bh*8 + ck)*256 + tid] = ar;
}

// ---------------------------------------------------------------------------
// attn_f: real gram -> softmax; imag part exactly uniform 1/16; IDFT-16 over c
__global__ void k_attn_f(const float* __restrict__ gramP, const float* __restrict__ recip,
                         const float* __restrict__ tempf, float* __restrict__ attn2) {
    int bh = blockIdx.x; int tid = threadIdx.x;
    int c = tid >> 4, d = tid & 15;
    int hh = bh & 7;
    float gr = 0.f;
    for (int ck = 0; ck < 8; ++ck) gr += gramP[(long)(bh*8+ck)*256 + tid];
    float vr = gr * recip[bh*16+c] * recip[bh*16+d] * tempf[hh];
    float mr = vr;
    for (int off = 8; off >= 1; off >>= 1) mr = fmaxf(mr, __shfl_xor(mr, off));
    float er = __expf(vr - mr);
    float ssr = er;
    for (int off = 8; off >= 1; off >>= 1) ssr += __shfl_xor(ssr, off);
    float arv = er / ssr;
    const float u = 1.0f/16.0f;
    __shared__ float sR[256];
    __shared__ float2 t16[16];
    sR[tid] = arv;
    if (tid < 16) {
        float a = PI2F() * (float)tid / 16.0f;
        t16[tid] = make_float2(__cosf(a), __sinf(a));
    }
    __syncthreads();
    float ar2 = 0.f, ai2 = 0.f;
    #pragma unroll
    for (int cc = 0; cc < 16; ++cc) {
        float2 t = t16[(cc*c) & 15];
        float xr = sR[cc*16 + d];
        ar2 = fmaf(xr, t.x, fmaf(-u, t.y, ar2));
        ai2 = fmaf(xr, t.y, fmaf( u, t.x, ai2));
    }
    long o = ((long)bh*256 + tid)*2;
    attn2[o]   = ar2 * (1.0f/16.0f);
    attn2[o+1] = ai2 * (1.0f/16.0f);
}

// ---------------------------------------------------------------------------
// Y[c][n] = sum_d attn2[c][d] * qf[d][n]   (complex)
__global__ void k_yf(const float* __restrict__ attn2, const float* __restrict__ Xr,
                     const float* __restrict__ Xi, float* __restrict__ Yr,
                     float* __restrict__ Yi) {
    int bh = blockIdx.x >> 6;
    int nb = blockIdx.x & 63;
    int tid = threadIdx.x;
    __shared__ float aR[256], aI[256];
    { long o = ((long)bh*256 + tid)*2; aR[tid] = attn2[o]; aI[tid] = attn2[o+1]; }
    __syncthreads();
    long n = (long)nb*256 + tid;
    long rowb = (long)bh*16;
    float qr[16], qi[16];
    #pragma unroll
    for (int dd = 0; dd < 16; ++dd) {
        qr[dd] = Xr[(rowb+dd)*P + n];
        qi[dd] = Xi[(rowb+dd)*P + n];
    }
    for (int cc = 0; cc < 16; ++cc) {
        float ar = 0.f, ai = 0.f;
        #pragma unroll
        for (int dd = 0; dd < 16; ++dd) {
            float tr = aR[cc*16+dd], ti = aI[cc*16+dd];
            ar = fmaf(tr, qr[dd], fmaf(-ti, qi[dd], ar));
            ai = fmaf(tr, qi[dd], fmaf( ti, qr[dd], ai));
        }
        Yr[(rowb+cc)*P + n] = ar;
        Yi[(rowb+cc)*P + n] = ai;
    }
}

// ---------------------------------------------------------------------------
// q/k/v 1x1 convs (one launch; which = q/k/v). 16 outch per thread.
__global__ void k_conv1x1qkv(const float* __restrict__ x,
                             const float* __restrict__ Wq, const float* __restrict__ bq,
                             const float* __restrict__ Wk, const float* __restrict__ bk,
                             const float* __restrict__ Wv, const float* __restrict__ bv,
                             float* __restrict__ Oq, float* __restrict__ Ok,
                             float* __restrict__ Ov) {
    int pc = blockIdx.x;
    int og = blockIdx.y & 7, which = blockIdx.y >> 3;
    int b = blockIdx.z;
    const float* W    = which == 0 ? Wq : which == 1 ? Wk : Wv;
    const float* bias = which == 0 ? bq : which == 1 ? bk : bv;
    float* O          = which == 0 ? Oq : which == 1 ? Ok : Ov;
    long p = (long)pc*256 + threadIdx.x;
    float acc[16];
    #pragma unroll
    for (int j = 0; j < 16; ++j) acc[j] = bias[og*16+j];
    const float* xb = x + (long)b*C*P + p;
    for (int c = 0; c < 128; ++c) {
        float xv = xb[(long)c*P];
        #pragma unroll
        for (int j = 0; j < 16; ++j)
            acc[j] = fmaf(W[(og*16+j)*128 + c], xv, acc[j]);
    }
    long ob = (long)b*C*P + (long)(og*16)*P + p;
    #pragma unroll
    for (int j = 0; j < 16; ++j) O[ob + (long)j*P] = acc[j];
}

// ---------------------------------------------------------------------------
// Grouped conv: out ch g<64 = 3x3(pad1) over in ch (2g,2g+1); g>=64 = 5x5(pad2)
__global__ void k_gconv(const float* __restrict__ in, const float* __restrict__ w3,
                        const float* __restrict__ w5, float* __restrict__ out) {
    int bid = blockIdx.x;
    int pc = bid & 63;
    int ch = (bid >> 6) & 127;
    int b  = bid >> 13;
    int p = pc*256 + threadIdx.x;
    int h = p >> 7, w = p & 127;
    float acc = 0.f;
    if (ch < 64) {
        int g = ch;
        const float* ib = in + ((long)b*C + 2*g)*P;
        #pragma unroll
        for (int ic = 0; ic < 2; ++ic) {
            const float* wp = w3 + (g*2 + ic)*9;
            #pragma unroll
            for (int ky = 0; ky < 3; ++ky) {
                int h2 = h + ky - 1;
                if (h2 < 0 || h2 > 127) continue;
                #pragma unroll
                for (int kx = 0; kx < 3; ++kx) {
                    int w2_ = w + kx - 1;
                    if (w2_ < 0 || w2_ > 127) continue;
                    acc = fmaf(wp[ky*3+kx], ib[(long)ic*P + h2*128 + w2_], acc);
                }
            }
        }
    } else {
        int g = ch - 64;
        const float* ib = in + ((long)b*C + 2*g)*P;
        #pragma unroll
        for (int ic = 0; ic < 2; ++ic) {
            const float* wp = w5 + (g*2 + ic)*25;
            #pragma unroll
            for (int ky = 0; ky < 5; ++ky) {
                int h2 = h + ky - 2;
                if (h2 < 0 || h2 > 127) continue;
                #pragma unroll
                for (int kx = 0; kx < 5; ++kx) {
                    int w2_ = w + kx - 2;
                    if (w2_ < 0 || w2_ > 127) continue;
                    acc = fmaf(wp[ky*5+kx], ib[(long)ic*P + h2*128 + w2_], acc);
                }
            }
        }
    }
    out[((long)b*C + ch)*P + p] = acc;
}

// ---------------------------------------------------------------------------
__global__ void k_gram_r(const float* __restrict__ Q, const float* __restrict__ K,
                         float* __restrict__ gramP) {
    int bh = blockIdx.x >> 3, ck = blockIdx.x & 7;
    int tid = threadIdx.x; int c = tid >> 4, d = tid & 15;
    long bc = ((long)bh*16 + c) * P;
    long bd = ((long)bh*16 + d) * P;
    int n0 = ck*2048;
    float a = 0.f;
    for (int n = n0; n < n0+2048; ++n)
        a = fmaf(Q[bc+n], K[bd+n], a);
    gramP[(long)(bh*8+ck)*256 + tid] = a;
}

__global__ void k_attn_s(const float* __restrict__ gramP, const float* __restrict__ rq,
                         const float* __restrict__ rk, const float* __restrict__ temps,
                         float* __restrict__ attn) {
    int bh = blockIdx.x; int tid = threadIdx.x;
    int c = tid >> 4, d = tid & 15;
    float g = 0.f;
    for (int ck = 0; ck < 8; ++ck) g += gramP[(long)(bh*8+ck)*256 + tid];
    g *= rq[bh*16+c] * rk[bh*16+d] * temps[bh & 7];
    float m = g;
    for (int off = 8; off >= 1; off >>= 1) m = fmaxf(m, __shfl_xor(m, off));
    float e = __expf(g - m);
    float s = e;
    for (int off = 8; off >= 1; off >>= 1) s += __shfl_xor(s, off);
    attn[(long)bh*256 + tid] = e / s;
}

__global__ void k_outs(const float* __restrict__ attn, const float* __restrict__ V,
                       float* __restrict__ out) {
    int bh = blockIdx.x >> 6, nb = blockIdx.x & 63;
    int tid = threadIdx.x;
    __shared__ float aS[256];
    aS[tid] = attn[(long)bh*256 + tid];
    __syncthreads();
    long n = (long)nb*256 + tid;
    long rowb = (long)bh*16;
    float vv[16];
    #pragma unroll
    for (int dd = 0; dd < 16; ++dd) vv[dd] = V[(rowb+dd)*P + n];
    for (int cc = 0; cc < 16; ++cc) {
        float a = 0.f;
        #pragma unroll
        for (int dd = 0; dd < 16; ++dd) a = fmaf(aS[cc*16+dd], vv[dd], a);
        out[(rowb+cc)*P + n] = a;
    }
}

// ---------------------------------------------------------------------------
// Projection with 2 stacked inputs: out = W[:, :128]*A + W[:, 128:]*Bc (+out)
template<bool ADD>
__global__ void k_proj2in(const float* __restrict__ A, const float* __restrict__ Bc,
                          const float* __restrict__ W, float* __restrict__ out) {
    int pc = blockIdx.x, og = blockIdx.y, b = blockIdx.z;
    long p = (long)pc*256 + threadIdx.x;
    float acc[16];
    #pragma unroll
    for (int j = 0; j < 16; ++j) acc[j] = 0.f;
    long xb = (long)b*C*P + p;
    for (int c = 0; c < 128; ++c) {
        float v0 = A [xb + (long)c*P];
        float v1 = Bc[xb + (long)c*P];
        #pragma unroll
        for (int j = 0; j < 16; ++j) {
            int o = og*16 + j;
            acc[j] = fmaf(W[o*256 + c], v0, fmaf(W[o*256 + 128 + c], v1, acc[j]));
        }
    }
    long ob = (long)b*C*P + (long)(og*16)*P + p;
    #pragma unroll
    for (int j = 0; j < 16; ++j) {
        if (ADD) out[ob + (long)j*P] += acc[j];
        else     out[ob + (long)j*P]  = acc[j];
    }
}

// ---------------------------------------------------------------------------
static long ws_need_bytes(int bc) {
    long pb = (long)bc * C * P;
    long extras = (long)bc*8*P           // Mg
                + (long)bc*128*3         // normF, recQ, recK
                + (long)bc*8*8*256       // gramC (real)
                + (long)bc*8*256*2       // attn2
                + (long)bc*8*8*256       // gramS
                + (long)bc*8*256;        // attnS
    return (5*pb + extras) * 4;
}

extern "C" void kernel_launch(void* const* d_in, const int* in_sizes, int n_in,
                              void* d_out, int out_size, void* d_ws, size_t ws_size,
                              hipStream_t stream) {
    const float* x      = (const float*)d_in[0];
    const float* temp_f = (const float*)d_in[1];
    const float* w1     = (const float*)d_in[2];
    const float* b1     = (const float*)d_in[3];
    const float* bng    = (const float*)d_in[4];
    const float* bnb    = (const float*)d_in[5];
    const float* bnm    = (const float*)d_in[6];
    const float* bnv    = (const float*)d_in[7];
    const float* w2     = (const float*)d_in[8];
    const float* b2     = (const float*)d_in[9];
    const float* projf  = (const float*)d_in[10];
    const float* temp_s = (const float*)d_in[11];
    const float* q1w = (const float*)d_in[12]; const float* q1b = (const float*)d_in[13];
    const float* k1w = (const float*)d_in[14]; const float* k1b = (const float*)d_in[15];
    const float* v1w = (const float*)d_in[16]; const float* v1b = (const float*)d_in[17];
    const float* q3w = (const float*)d_in[18]; const float* q5w = (const float*)d_in[19];
    const float* k3w = (const float*)d_in[20]; const float* k5w = (const float*)d_in[21];
    const float* v3w = (const float*)d_in[22]; const float* v5w = (const float*)d_in[23];
    const float* c3w = (const float*)d_in[24]; const float* c5w = (const float*)d_in[25];
    const float* projs  = (const float*)d_in[26];
    float* out = (float*)d_out;
    float* ws = (float*)d_ws;

    int bc = 1;
    if ((long)ws_size >= ws_need_bytes(8)) bc = 8;
    else if ((long)ws_size >= ws_need_bytes(4)) bc = 4;
    else if ((long)ws_size >= ws_need_bytes(2)) bc = 2;
    const int NB = bc;
    const long pb = (long)bc * C * P;

    float* t0 = ws + 0*pb;
    float* t1 = ws + 1*pb;
    float* t2 = ws + 2*pb;
    float* t3 = ws + 3*pb;
    float* t4 = ws + 4*pb;
    float* Mg    = ws + 5*pb;
    float* normF = Mg + (long)bc*8*P;
    float* recQ  = normF + (long)bc*128;
    float* recK  = recQ + (long)bc*128;
    float* gramC = recK + (long)bc*128;
    float* attn2 = gramC + (long)bc*8*8*256;
    float* gramS = attn2 + (long)bc*8*256*2;
    float* attnS = gramS + (long)bc*8*8*256;

    for (int ckk = 0; ckk < 8/bc; ++ckk) {
        const float* xc = x + (long)ckk * bc * C * P;
        float* outc = out + (long)ckk * bc * C * P;

        // ================= frequency branch =================
        k_fftrow<0><<<NB*C*32, 256, 0, stream>>>(xc, nullptr, t0, t1);      // rows fwd
        k_fftcol<-1,false><<<NB*C*4, 256, 0, stream>>>(t0, t1, nullptr, nullptr,
                                                       nullptr, t2, t3);    // XF=(t2,t3)
        k_gate_mid<<<(NB*P)/256, 256, 0, stream>>>(t2, w1, b1, bng, bnb, bnm, bnv, Mg);
        k_fftcol<1,true><<<NB*C*4, 256, 0, stream>>>(t2, t3, Mg, w2, b2,
                                                     t0, t1);               // gate h-IFFT
        k_fftrow<1><<<NB*C*32, 256, 0, stream>>>(t0, t1, t4, nullptr);      // OFL=t4
        k_norms_c<<<NB*C, 256, 0, stream>>>(t2, t3, normF);
        k_gram_cr<<<NB*8*8, 256, 0, stream>>>(t2, t3, gramC);
        k_attn_f<<<NB*8, 256, 0, stream>>>(gramC, normF, temp_f, attn2);
        k_yf<<<NB*8*64, 256, 0, stream>>>(attn2, t2, t3, t0, t1);           // Y=(t0,t1)
        k_fftcol<1,false><<<NB*C*4, 256, 0, stream>>>(t0, t1, nullptr, nullptr,
                                                      nullptr, t2, t3);     // CT pass1
        k_fftrow<2><<<NB*C*32, 256, 0, stream>>>(t2, t3, t0, nullptr);      // OF=t0
        k_proj2in<false><<<dim3(64, 8, NB), 256, 0, stream>>>(t0, t4, projf, outc);

        // ================= spatial branch =================
        k_conv1x1qkv<<<dim3(64, 24, NB), 256, 0, stream>>>(xc, q1w, q1b, k1w, k1b,
                                                           v1w, v1b, t0, t1, t2);
        k_gconv<<<NB*128*64, 256, 0, stream>>>(t0, q3w, q5w, t3);   // QS=t3
        k_gconv<<<NB*128*64, 256, 0, stream>>>(t1, k3w, k5w, t4);   // KS=t4
        k_gconv<<<NB*128*64, 256, 0, stream>>>(t2, v3w, v5w, t0);   // VS=t0
        k_gconv<<<NB*128*64, 256, 0, stream>>>(xc, c3w, c5w, t1);   // OSL=t1
        k_norms_r<<<NB*C, 256, 0, stream>>>(t3, recQ);
        k_norms_r<<<NB*C, 256, 0, stream>>>(t4, recK);
        k_gram_r<<<NB*8*8, 256, 0, stream>>>(t3, t4, gramS);
        k_attn_s<<<NB*8, 256, 0, stream>>>(gramS, recQ, recK, temp_s, attnS);
        k_outs<<<NB*8*64, 256, 0, stream>>>(attnS, t0, t2);         // OS=t2
        k_proj2in<true><<<dim3(64, 8, NB), 256, 0, stream>>>(t2, t1, projs, outc);
    }
}

// Round 6
// 2110.031 us; speedup vs baseline: 3.2845x; 1.4966x over previous
//
#include <hip/hip_runtime.h>
#include <math.h>

#define B 8
#define C 128
#define HEADS 8
#define HD 16
#define HH 128
#define WW 128
#define P 16384          // HH*WW

static __device__ __forceinline__ float PI2F() { return 6.28318530717958647692f; }

// ===========================================================================
// Radix-2 DIT FFT-128 along the STRIDED (h) axis. 32 columns per block,
// 256 threads. GATE variant fuses sigmoid(W2*Mg+b2)*XF into staging.
template<int SIGN, bool GATE>
__global__ __launch_bounds__(256) void k_fftcol(
        const float* __restrict__ inR, const float* __restrict__ inI,
        const float* __restrict__ Mg, const float* __restrict__ w2,
        const float* __restrict__ b2,
        float* __restrict__ outR, float* __restrict__ outI) {
    __shared__ float2 S[128*32];
    __shared__ float2 tw[64];
    int bid = blockIdx.x;
    int img = bid >> 2;
    int qo  = (bid & 3) * 32;
    int tid = threadIdx.x;
    if (tid < 64) {
        float a = PI2F() * (float)tid / 128.0f;
        float s_, c_; __sincosf(a, &s_, &c_);
        tw[tid] = make_float2(c_, SIGN > 0 ? s_ : -s_);
    }
    long base = (long)img * P;
    float w2r[8]; float b2c = 0.f;
    const float* mb = nullptr;
    if (GATE) {
        int c = img & 127;
        #pragma unroll
        for (int j = 0; j < 8; ++j) w2r[j] = w2[c*8 + j];
        b2c = b2[c];
        mb = Mg + (long)(img >> 7)*8*P;
    }
    #pragma unroll
    for (int t = 0; t < 16; ++t) {
        int idx = tid + t*256;
        int h = idx >> 5, cc = idx & 31;
        int off = h*128 + qo + cc;
        float xr = inR[base + off];
        float xi = inI[base + off];
        if (GATE) {
            float z = b2c;
            #pragma unroll
            for (int j = 0; j < 8; ++j) z = fmaf(w2r[j], mb[(long)j*P + off], z);
            float g = 1.0f / (1.0f + __expf(-z));
            xr *= g; xi *= g;
        }
        int hr = __brev(h) >> 25;          // 7-bit reversal
        S[hr*32 + cc] = make_float2(xr, xi);
    }
    __syncthreads();
    int ln = tid & 31, wid = tid >> 5;
    for (int s = 0; s < 7; ++s) {
        int half = 1 << s;
        #pragma unroll
        for (int q = 0; q < 8; ++q) {
            int j = wid*8 + q;
            int k = j & (half - 1);
            int g = j >> s;
            int i0 = (g << (s+1)) + k;
            int i1 = i0 + half;
            float2 u = S[i0*32 + ln];
            float2 v = S[i1*32 + ln];
            float2 w = tw[k << (6 - s)];
            float vr = v.x*w.x - v.y*w.y;
            float vi = v.x*w.y + v.y*w.x;
            S[i0*32 + ln] = make_float2(u.x + vr, u.y + vi);
            S[i1*32 + ln] = make_float2(u.x - vr, u.y - vi);
        }
        __syncthreads();
    }
    #pragma unroll
    for (int t = 0; t < 16; ++t) {
        int idx = tid + t*256;
        int k = idx >> 5, cc = idx & 31;
        float2 z = S[k*32 + cc];
        outR[base + k*128 + qo + cc] = z.x;
        outI[base + k*128 + qo + cc] = z.y;
    }
}

// ===========================================================================
// Radix-2 DIT FFT-128 along the CONTIGUOUS (w) axis. 4 rows/block, 256 thr.
// MODE 0: real fwd; MODE 1: inverse+abs/16384; MODE 2: CT pass2 (premul
// twiddle, inverse, abs, transposed float4 store).
template<int MODE>
__global__ __launch_bounds__(256) void k_fftrow(
        const float* __restrict__ inR, const float* __restrict__ inI,
        float* __restrict__ out, float* __restrict__ outI) {
    __shared__ float2 S[4*128];
    __shared__ float2 tw[64];
    int bid = blockIdx.x;
    int img = bid >> 5;
    int r0  = (bid & 31) * 4;
    int tid = threadIdx.x;
    if (tid < 64) {
        float a = PI2F() * (float)tid / 128.0f;
        float s_, c_; __sincosf(a, &s_, &c_);
        tw[tid] = make_float2(c_, MODE == 0 ? -s_ : s_);
    }
    long base = (long)img * P;
    #pragma unroll
    for (int t = 0; t < 2; ++t) {
        int idx = tid + t*256;
        int r = idx >> 7, w = idx & 127;
        long off = base + (long)(r0 + r)*128 + w;
        float xr = inR[off];
        float xi = (MODE == 0) ? 0.f : inI[off];
        if (MODE == 2) {
            int k2 = r0 + r;
            float ang = (PI2F()/16384.0f) * (float)(w * k2);
            float s_, c_; __sincosf(ang, &s_, &c_);
            float yr = xr*c_ - xi*s_;
            float yi = xr*s_ + xi*c_;
            xr = yr; xi = yi;
        }
        S[r*128 + (__brev(w) >> 25)] = make_float2(xr, xi);
    }
    __syncthreads();
    int r = tid >> 6, j = tid & 63;
    for (int s = 0; s < 7; ++s) {
        int half = 1 << s;
        int k = j & (half - 1);
        int g = j >> s;
        int i0 = (g << (s+1)) + k;
        int i1 = i0 + half;
        float2 u = S[r*128 + i0];
        float2 v = S[r*128 + i1];
        float2 w_ = tw[k << (6 - s)];
        float vr = v.x*w_.x - v.y*w_.y;
        float vi = v.x*w_.y + v.y*w_.x;
        S[r*128 + i0] = make_float2(u.x + vr, u.y + vi);
        S[r*128 + i1] = make_float2(u.x - vr, u.y - vi);
        __syncthreads();
    }
    if (MODE == 0) {
        #pragma unroll
        for (int t = 0; t < 2; ++t) {
            int idx = tid + t*256;
            int rr = idx >> 7, k = idx & 127;
            float2 z = S[rr*128 + k];
            long off = base + (long)(r0 + rr)*128 + k;
            out[off] = z.x; outI[off] = z.y;
        }
    } else if (MODE == 1) {
        #pragma unroll
        for (int t = 0; t < 2; ++t) {
            int idx = tid + t*256;
            int rr = idx >> 7, p = idx & 127;
            float2 z = S[rr*128 + p];
            out[base + (long)(r0 + rr)*128 + p] =
                sqrtf(z.x*z.x + z.y*z.y) * (1.0f/16384.0f);
        }
    } else {
        if (tid < 128) {
            int k1 = tid;
            float4 v;
            float2 z0 = S[0*128 + k1], z1 = S[1*128 + k1];
            float2 z2 = S[2*128 + k1], z3 = S[3*128 + k1];
            v.x = sqrtf(z0.x*z0.x + z0.y*z0.y) * (1.0f/16384.0f);
            v.y = sqrtf(z1.x*z1.x + z1.y*z1.y) * (1.0f/16384.0f);
            v.z = sqrtf(z2.x*z2.x + z2.y*z2.y) * (1.0f/16384.0f);
            v.w = sqrtf(z3.x*z3.x + z3.y*z3.y) * (1.0f/16384.0f);
            *(float4*)(out + base + (long)k1*128 + r0) = v;
        }
    }
}

// ---------------------------------------------------------------------------
// SE gate stage 1, float4-pixel GEMM pattern. Thread = 4 px, 8 out-ch.
__global__ __launch_bounds__(256) void k_gate_mid(
        const float* __restrict__ XFr, const float* __restrict__ w1,
        const float* __restrict__ b1, const float* __restrict__ gamma,
        const float* __restrict__ beta, const float* __restrict__ mean,
        const float* __restrict__ var, float* __restrict__ M) {
    __shared__ float w1s[8*128];
    int tid = threadIdx.x;
    for (int i = tid; i < 1024; i += 256) w1s[i] = w1[i];
    __syncthreads();
    int tile = blockIdx.x;             // NB*16
    int b = tile >> 4;
    long pbase = (long)(tile & 15)*1024 + tid*4;
    const float4* xp = (const float4*)(XFr + (long)b*C*P + pbase);
    float4 acc[8];
    #pragma unroll
    for (int j = 0; j < 8; ++j) { float bj = b1[j]; acc[j] = make_float4(bj,bj,bj,bj); }
    for (int c = 0; c < 128; ++c) {
        float4 xv = xp[c*(P/4)];
        #pragma unroll
        for (int j = 0; j < 8; ++j) {
            float w = w1s[j*128 + c];
            acc[j].x = fmaf(w, xv.x, acc[j].x);
            acc[j].y = fmaf(w, xv.y, acc[j].y);
            acc[j].z = fmaf(w, xv.z, acc[j].z);
            acc[j].w = fmaf(w, xv.w, acc[j].w);
        }
    }
    #pragma unroll
    for (int j = 0; j < 8; ++j) {
        float sc = rsqrtf(var[j] + 1e-5f) * gamma[j];
        float sh = beta[j] - mean[j]*sc;
        float4 v;
        v.x = fmaxf(fmaf(acc[j].x, sc, sh), 0.f);
        v.y = fmaxf(fmaf(acc[j].y, sc, sh), 0.f);
        v.z = fmaxf(fmaf(acc[j].z, sc, sh), 0.f);
        v.w = fmaxf(fmaf(acc[j].w, sc, sh), 0.f);
        *(float4*)(M + ((long)b*8 + j)*P + pbase) = v;
    }
}

// ---------------------------------------------------------------------------
// Row-wise L2 norm reciprocals (complex / real)
__global__ void k_norms_c(const float* __restrict__ Xr, const float* __restrict__ Xi,
                          float* __restrict__ recip) {
    int row = blockIdx.x; int tid = threadIdx.x;
    long base = (long)row * P;
    float s = 0.f;
    for (int n = tid; n < P; n += 256) {
        float r = Xr[base+n], i = Xi[base+n];
        s = fmaf(r, r, fmaf(i, i, s));
    }
    __shared__ float red[256];
    red[tid] = s; __syncthreads();
    for (int st = 128; st > 0; st >>= 1) {
        if (tid < st) red[tid] += red[tid+st];
        __syncthreads();
    }
    if (tid == 0) recip[row] = 1.0f / fmaxf(sqrtf(red[0]), 1e-12f);
}

__global__ void k_norms_r(const float* __restrict__ X, float* __restrict__ recip) {
    int row = blockIdx.x; int tid = threadIdx.x;
    long base = (long)row * P;
    float s = 0.f;
    for (int n = tid; n < P; n += 256) { float v = X[base+n]; s = fmaf(v, v, s); }
    __shared__ float red[256];
    red[tid] = s; __syncthreads();
    for (int st = 128; st > 0; st >>= 1) {
        if (tid < st) red[tid] += red[tid+st];
        __syncthreads();
    }
    if (tid == 0) recip[row] = 1.0f / fmaxf(sqrtf(red[0]), 1e-12f);
}

// ---------------------------------------------------------------------------
// Complex Gram, REAL part only (imag exactly 0 by Hermitian symmetry)
__global__ void k_gram_cr(const float* __restrict__ Xr, const float* __restrict__ Xi,
                          float* __restrict__ gramP) {
    int bh = blockIdx.x >> 3, ck = blockIdx.x & 7;
    int tid = threadIdx.x; int c = tid >> 4, d = tid & 15;
    long bc = ((long)bh*16 + c) * P;
    long bd = ((long)bh*16 + d) * P;
    int n0 = ck * 2048;
    float ar = 0.f;
    for (int n = n0; n < n0 + 2048; ++n) {
        ar = fmaf(Xr[bc+n], Xr[bd+n], fmaf(-Xi[bc+n], Xi[bd+n], ar));
    }
    gramP[(long)(bh*8 + ck)*256 + tid] = ar;
}

// ---------------------------------------------------------------------------
// attn_f: real gram -> softmax; imag part exactly uniform 1/16; IDFT-16 over c
__global__ void k_attn_f(const float* __restrict__ gramP, const float* __restrict__ recip,
                         const float* __restrict__ tempf, float* __restrict__ attn2) {
    int bh = blockIdx.x; int tid = threadIdx.x;
    int c = tid >> 4, d = tid & 15;
    int hh = bh & 7;
    float gr = 0.f;
    for (int ck = 0; ck < 8; ++ck) gr += gramP[(long)(bh*8+ck)*256 + tid];
    float vr = gr * recip[bh*16+c] * recip[bh*16+d] * tempf[hh];
    float mr = vr;
    for (int off = 8; off >= 1; off >>= 1) mr = fmaxf(mr, __shfl_xor(mr, off));
    float er = __expf(vr - mr);
    float ssr = er;
    for (int off = 8; off >= 1; off >>= 1) ssr += __shfl_xor(ssr, off);
    float arv = er / ssr;
    const float u = 1.0f/16.0f;
    __shared__ float sR[256];
    __shared__ float2 t16[16];
    sR[tid] = arv;
    if (tid < 16) {
        float a = PI2F() * (float)tid / 16.0f;
        t16[tid] = make_float2(__cosf(a), __sinf(a));
    }
    __syncthreads();
    float ar2 = 0.f, ai2 = 0.f;
    #pragma unroll
    for (int cc = 0; cc < 16; ++cc) {
        float2 t = t16[(cc*c) & 15];
        float xr = sR[cc*16 + d];
        ar2 = fmaf(xr, t.x, fmaf(-u, t.y, ar2));
        ai2 = fmaf(xr, t.y, fmaf( u, t.x, ai2));
    }
    long o = ((long)bh*256 + tid)*2;
    attn2[o]   = ar2 * (1.0f/16.0f);
    attn2[o+1] = ai2 * (1.0f/16.0f);
}

// ---------------------------------------------------------------------------
// Y[c][n] = sum_d attn2[c][d] * qf[d][n]   (complex)
__global__ void k_yf(const float* __restrict__ attn2, const float* __restrict__ Xr,
                     const float* __restrict__ Xi, float* __restrict__ Yr,
                     float* __restrict__ Yi) {
    int bh = blockIdx.x >> 6;
    int nb = blockIdx.x & 63;
    int tid = threadIdx.x;
    __shared__ float aR[256], aI[256];
    { long o = ((long)bh*256 + tid)*2; aR[tid] = attn2[o]; aI[tid] = attn2[o+1]; }
    __syncthreads();
    long n = (long)nb*256 + tid;
    long rowb = (long)bh*16;
    float qr[16], qi[16];
    #pragma unroll
    for (int dd = 0; dd < 16; ++dd) {
        qr[dd] = Xr[(rowb+dd)*P + n];
        qi[dd] = Xi[(rowb+dd)*P + n];
    }
    for (int cc = 0; cc < 16; ++cc) {
        float ar = 0.f, ai = 0.f;
        #pragma unroll
        for (int dd = 0; dd < 16; ++dd) {
            float tr = aR[cc*16+dd], ti = aI[cc*16+dd];
            ar = fmaf(tr, qr[dd], fmaf(-ti, qi[dd], ar));
            ai = fmaf(tr, qi[dd], fmaf( ti, qr[dd], ai));
        }
        Yr[(rowb+cc)*P + n] = ar;
        Yi[(rowb+cc)*P + n] = ai;
    }
}

// ---------------------------------------------------------------------------
// q/k/v 1x1 convs, float4-pixel GEMM pattern. Thread = 4 px, 16 out-ch.
__global__ __launch_bounds__(256) void k_conv1x1qkv(
        const float* __restrict__ x,
        const float* __restrict__ Wq, const float* __restrict__ bq,
        const float* __restrict__ Wk, const float* __restrict__ bk,
        const float* __restrict__ Wv, const float* __restrict__ bv,
        float* __restrict__ Oq, float* __restrict__ Ok,
        float* __restrict__ Ov) {
    __shared__ float Ws[16*128];
    int og = blockIdx.y & 7, which = blockIdx.y >> 3;
    int b = blockIdx.z;
    const float* W    = which == 0 ? Wq : which == 1 ? Wk : Wv;
    const float* bias = which == 0 ? bq : which == 1 ? bk : bv;
    float* O          = which == 0 ? Oq : which == 1 ? Ok : Ov;
    int tid = threadIdx.x;
    for (int i = tid; i < 2048; i += 256) Ws[i] = W[og*2048 + i];
    __syncthreads();
    long pbase = (long)blockIdx.x*1024 + tid*4;
    const float4* xp = (const float4*)(x + (long)b*C*P + pbase);
    float4 acc[16];
    #pragma unroll
    for (int j = 0; j < 16; ++j) { float bj = bias[og*16+j]; acc[j] = make_float4(bj,bj,bj,bj); }
    for (int c = 0; c < 128; ++c) {
        float4 xv = xp[c*(P/4)];
        #pragma unroll
        for (int j = 0; j < 16; ++j) {
            float w = Ws[j*128 + c];
            acc[j].x = fmaf(w, xv.x, acc[j].x);
            acc[j].y = fmaf(w, xv.y, acc[j].y);
            acc[j].z = fmaf(w, xv.z, acc[j].z);
            acc[j].w = fmaf(w, xv.w, acc[j].w);
        }
    }
    float* op = O + (long)b*C*P + (long)og*16*P + pbase;
    #pragma unroll
    for (int j = 0; j < 16; ++j) *(float4*)(op + (long)j*P) = acc[j];
}

// ---------------------------------------------------------------------------
// Grouped conv, LDS-tiled; one block computes BOTH the 3x3 out-ch (g) and the
// 5x5 out-ch (64+g) from the shared 2-channel input tile. 16-row tiles.
__global__ __launch_bounds__(256) void k_gconv(
        const float* __restrict__ in, const float* __restrict__ w3,
        const float* __restrict__ w5, float* __restrict__ out) {
    __shared__ float S[2*20*132];
    __shared__ float ws3[18], ws5[50];
    int ht = blockIdx.x;       // 0..7
    int g  = blockIdx.y;       // 0..63
    int b  = blockIdx.z;
    int tid = threadIdx.x;
    int h0 = ht*16;
    const float* ib = in + ((long)b*C + 2*g)*P;
    if (tid < 18) ws3[tid] = w3[g*18 + tid];
    else if (tid < 68) ws5[tid-18] = w5[g*50 + tid - 18];
    for (int i = tid; i < 2*20*132; i += 256) {
        int ic = i / 2640, rem = i % 2640;
        int t = rem / 132, cc = rem % 132;
        int h = h0 - 2 + t, w = cc - 2;
        float v = 0.f;
        if (h >= 0 && h < 128 && w >= 0 && w < 128)
            v = ib[(long)ic*P + h*128 + w];
        S[i] = v;
    }
    __syncthreads();
    int w = tid & 127, rh = tid >> 7;
    int lr0 = rh*8;
    float acc3[8], acc5[8];
    #pragma unroll
    for (int r = 0; r < 8; ++r) { acc3[r] = 0.f; acc5[r] = 0.f; }
    #pragma unroll
    for (int ic = 0; ic < 2; ++ic) {
        const float* Sc = S + ic*2640;
        #pragma unroll
        for (int kx = 0; kx < 3; ++kx) {
            float col[10];
            #pragma unroll
            for (int i = 0; i < 10; ++i)
                col[i] = Sc[(lr0 + 1 + i)*132 + (w + 1 + kx)];
            #pragma unroll
            for (int ky = 0; ky < 3; ++ky) {
                float wv = ws3[ic*9 + ky*3 + kx];
                #pragma unroll
                for (int r = 0; r < 8; ++r)
                    acc3[r] = fmaf(wv, col[r + ky], acc3[r]);
            }
        }
        #pragma unroll
        for (int kx = 0; kx < 5; ++kx) {
            float col[12];
            #pragma unroll
            for (int i = 0; i < 12; ++i)
                col[i] = Sc[(lr0 + i)*132 + (w + kx)];
            #pragma unroll
            for (int ky = 0; ky < 5; ++ky) {
                float wv = ws5[ic*25 + ky*5 + kx];
                #pragma unroll
                for (int r = 0; r < 8; ++r)
                    acc5[r] = fmaf(wv, col[r + ky], acc5[r]);
            }
        }
    }
    long ob3 = ((long)b*C + g)*P;
    long ob5 = ((long)b*C + 64 + g)*P;
    #pragma unroll
    for (int r = 0; r < 8; ++r) {
        int h = h0 + lr0 + r;
        out[ob3 + h*128 + w] = acc3[r];
        out[ob5 + h*128 + w] = acc5[r];
    }
}

// ---------------------------------------------------------------------------
// Real Gram partials for spatial attention
__global__ void k_gram_r(const float* __restrict__ Q, const float* __restrict__ K,
                         float* __restrict__ gramP) {
    int bh = blockIdx.x >> 3, ck = blockIdx.x & 7;
    int tid = threadIdx.x; int c = tid >> 4, d = tid & 15;
    long bc = ((long)bh*16 + c) * P;
    long bd = ((long)bh*16 + d) * P;
    int n0 = ck*2048;
    float a = 0.f;
    for (int n = n0; n < n0+2048; ++n)
        a = fmaf(Q[bc+n], K[bd+n], a);
    gramP[(long)(bh*8+ck)*256 + tid] = a;
}

__global__ void k_attn_s(const float* __restrict__ gramP, const float* __restrict__ rq,
                         const float* __restrict__ rk, const float* __restrict__ temps,
                         float* __restrict__ attn) {
    int bh = blockIdx.x; int tid = threadIdx.x;
    int c = tid >> 4, d = tid & 15;
    float g = 0.f;
    for (int ck = 0; ck < 8; ++ck) g += gramP[(long)(bh*8+ck)*256 + tid];
    g *= rq[bh*16+c] * rk[bh*16+d] * temps[bh & 7];
    float m = g;
    for (int off = 8; off >= 1; off >>= 1) m = fmaxf(m, __shfl_xor(m, off));
    float e = __expf(g - m);
    float s = e;
    for (int off = 8; off >= 1; off >>= 1) s += __shfl_xor(s, off);
    attn[(long)bh*256 + tid] = e / s;
}

__global__ void k_outs(const float* __restrict__ attn, const float* __restrict__ V,
                       float* __restrict__ out) {
    int bh = blockIdx.x >> 6, nb = blockIdx.x & 63;
    int tid = threadIdx.x;
    __shared__ float aS[256];
    aS[tid] = attn[(long)bh*256 + tid];
    __syncthreads();
    long n = (long)nb*256 + tid;
    long rowb = (long)bh*16;
    float vv[16];
    #pragma unroll
    for (int dd = 0; dd < 16; ++dd) vv[dd] = V[(rowb+dd)*P + n];
    for (int cc = 0; cc < 16; ++cc) {
        float a = 0.f;
        #pragma unroll
        for (int dd = 0; dd < 16; ++dd) a = fmaf(aS[cc*16+dd], vv[dd], a);
        out[(rowb+cc)*P + n] = a;
    }
}

// ---------------------------------------------------------------------------
// Projection with 2 stacked inputs, float4-pixel GEMM pattern.
// out = W[:, :128]*A + W[:, 128:]*Bc (+out if ADD)
template<bool ADD>
__global__ __launch_bounds__(256) void k_proj2in(
        const float* __restrict__ A, const float* __restrict__ Bc,
        const float* __restrict__ W, float* __restrict__ out) {
    __shared__ float Ws[16*256];
    int og = blockIdx.y, b = blockIdx.z;
    int tid = threadIdx.x;
    for (int i = tid; i < 4096; i += 256) Ws[i] = W[og*4096 + i];
    __syncthreads();
    long pbase = (long)blockIdx.x*1024 + tid*4;
    long xb = (long)b*C*P;
    const float4* Ap = (const float4*)(A + xb + pbase);
    const float4* Bp = (const float4*)(Bc + xb + pbase);
    float4 acc[16];
    #pragma unroll
    for (int j = 0; j < 16; ++j) acc[j] = make_float4(0.f,0.f,0.f,0.f);
    for (int c = 0; c < 128; ++c) {
        float4 a = Ap[c*(P/4)];
        float4 bb = Bp[c*(P/4)];
        #pragma unroll
        for (int j = 0; j < 16; ++j) {
            float w0 = Ws[j*256 + c], w1 = Ws[j*256 + 128 + c];
            acc[j].x = fmaf(w0, a.x, fmaf(w1, bb.x, acc[j].x));
            acc[j].y = fmaf(w0, a.y, fmaf(w1, bb.y, acc[j].y));
            acc[j].z = fmaf(w0, a.z, fmaf(w1, bb.z, acc[j].z));
            acc[j].w = fmaf(w0, a.w, fmaf(w1, bb.w, acc[j].w));
        }
    }
    float* op = out + xb + (long)og*16*P + pbase;
    #pragma unroll
    for (int j = 0; j < 16; ++j) {
        float4 v = acc[j];
        if (ADD) {
            float4 o = *(float4*)(op + (long)j*P);
            v.x += o.x; v.y += o.y; v.z += o.z; v.w += o.w;
        }
        *(float4*)(op + (long)j*P) = v;
    }
}

// ---------------------------------------------------------------------------
static long ws_need_bytes(int bc) {
    long pb = (long)bc * C * P;
    long extras = (long)bc*8*P           // Mg
                + (long)bc*128*3         // normF, recQ, recK
                + (long)bc*8*8*256       // gramC (real)
                + (long)bc*8*256*2       // attn2
                + (long)bc*8*8*256       // gramS
                + (long)bc*8*256;        // attnS
    return (5*pb + extras) * 4;
}

extern "C" void kernel_launch(void* const* d_in, const int* in_sizes, int n_in,
                              void* d_out, int out_size, void* d_ws, size_t ws_size,
                              hipStream_t stream) {
    const float* x      = (const float*)d_in[0];
    const float* temp_f = (const float*)d_in[1];
    const float* w1     = (const float*)d_in[2];
    const float* b1     = (const float*)d_in[3];
    const float* bng    = (const float*)d_in[4];
    const float* bnb    = (const float*)d_in[5];
    const float* bnm    = (const float*)d_in[6];
    const float* bnv    = (const float*)d_in[7];
    const float* w2     = (const float*)d_in[8];
    const float* b2     = (const float*)d_in[9];
    const float* projf  = (const float*)d_in[10];
    const float* temp_s = (const float*)d_in[11];
    const float* q1w = (const float*)d_in[12]; const float* q1b = (const float*)d_in[13];
    const float* k1w = (const float*)d_in[14]; const float* k1b = (const float*)d_in[15];
    const float* v1w = (const float*)d_in[16]; const float* v1b = (const float*)d_in[17];
    const float* q3w = (const float*)d_in[18]; const float* q5w = (const float*)d_in[19];
    const float* k3w = (const float*)d_in[20]; const float* k5w = (const float*)d_in[21];
    const float* v3w = (const float*)d_in[22]; const float* v5w = (const float*)d_in[23];
    const float* c3w = (const float*)d_in[24]; const float* c5w = (const float*)d_in[25];
    const float* projs  = (const float*)d_in[26];
    float* out = (float*)d_out;
    float* ws = (float*)d_ws;

    int bc = 1;
    if ((long)ws_size >= ws_need_bytes(8)) bc = 8;
    else if ((long)ws_size >= ws_need_bytes(4)) bc = 4;
    else if ((long)ws_size >= ws_need_bytes(2)) bc = 2;
    const int NB = bc;
    const long pb = (long)bc * C * P;

    float* t0 = ws + 0*pb;
    float* t1 = ws + 1*pb;
    float* t2 = ws + 2*pb;
    float* t3 = ws + 3*pb;
    float* t4 = ws + 4*pb;
    float* Mg    = ws + 5*pb;
    float* normF = Mg + (long)bc*8*P;
    float* recQ  = normF + (long)bc*128;
    float* recK  = recQ + (long)bc*128;
    float* gramC = recK + (long)bc*128;
    float* attn2 = gramC + (long)bc*8*8*256;
    float* gramS = attn2 + (long)bc*8*256*2;
    float* attnS = gramS + (long)bc*8*8*256;

    for (int ckk = 0; ckk < 8/bc; ++ckk) {
        const float* xc = x + (long)ckk * bc * C * P;
        float* outc = out + (long)ckk * bc * C * P;

        // ================= frequency branch =================
        k_fftrow<0><<<NB*C*32, 256, 0, stream>>>(xc, nullptr, t0, t1);      // rows fwd
        k_fftcol<-1,false><<<NB*C*4, 256, 0, stream>>>(t0, t1, nullptr, nullptr,
                                                       nullptr, t2, t3);    // XF=(t2,t3)
        k_gate_mid<<<NB*16, 256, 0, stream>>>(t2, w1, b1, bng, bnb, bnm, bnv, Mg);
        k_fftcol<1,true><<<NB*C*4, 256, 0, stream>>>(t2, t3, Mg, w2, b2,
                                                     t0, t1);               // gate h-IFFT
        k_fftrow<1><<<NB*C*32, 256, 0, stream>>>(t0, t1, t4, nullptr);      // OFL=t4
        k_norms_c<<<NB*C, 256, 0, stream>>>(t2, t3, normF);
        k_gram_cr<<<NB*8*8, 256, 0, stream>>>(t2, t3, gramC);
        k_attn_f<<<NB*8, 256, 0, stream>>>(gramC, normF, temp_f, attn2);
        k_yf<<<NB*8*64, 256, 0, stream>>>(attn2, t2, t3, t0, t1);           // Y=(t0,t1)
        k_fftcol<1,false><<<NB*C*4, 256, 0, stream>>>(t0, t1, nullptr, nullptr,
                                                      nullptr, t2, t3);     // CT pass1
        k_fftrow<2><<<NB*C*32, 256, 0, stream>>>(t2, t3, t0, nullptr);      // OF=t0
        k_proj2in<false><<<dim3(16, 8, NB), 256, 0, stream>>>(t0, t4, projf, outc);

        // ================= spatial branch =================
        k_conv1x1qkv<<<dim3(16, 24, NB), 256, 0, stream>>>(xc, q1w, q1b, k1w, k1b,
                                                           v1w, v1b, t0, t1, t2);
        k_gconv<<<dim3(8, 64, NB), 256, 0, stream>>>(t0, q3w, q5w, t3);   // QS=t3
        k_gconv<<<dim3(8, 64, NB), 256, 0, stream>>>(t1, k3w, k5w, t4);   // KS=t4
        k_gconv<<<dim3(8, 64, NB), 256, 0, stream>>>(t2, v3w, v5w, t0);   // VS=t0
        k_gconv<<<dim3(8, 64, NB), 256, 0, stream>>>(xc, c3w, c5w, t1);   // OSL=t1
        k_norms_r<<<NB*C, 256, 0, stream>>>(t3, recQ);
        k_norms_r<<<NB*C, 256, 0, stream>>>(t4, recK);
        k_gram_r<<<NB*8*8, 256, 0, stream>>>(t3, t4, gramS);
        k_attn_s<<<NB*8, 256, 0, stream>>>(gramS, recQ, recK, temp_s, attnS);
        k_outs<<<NB*8*64, 256, 0, stream>>>(attnS, t0, t2);         // OS=t2
        k_proj2in<true><<<dim3(16, 8, NB), 256, 0, stream>>>(t2, t1, projs, outc);
    }
}